// Round 9
// baseline (475.536 us; speedup 1.0000x reference)
//
#include <hip/hip_runtime.h>
#include <stdint.h>

// f32 I/O, bf16 MFMA internals. Attention v6: swapped QK^T, log2-domain
// in-register softmax, QBLK=128 (8 waves), cross-tile pipeline with
// STAGGERED COUNTED vmcnt waits (T4): per-body issue [K, kb x4, V] = 6 VMEM;
// waits vmcnt(11)/(7)/(6) before QK^T/softmax/PV; raw barrier, NO drain.
// No XCD swizzle (r8 showed it causes L2 hotspot w/o BW benefit).
// Masked-q rows = mean(V) (reference's -1e9 bias absorbs scores in f32).

typedef unsigned short u16;
typedef __attribute__((ext_vector_type(4))) float f32x4;
typedef __attribute__((ext_vector_type(8))) short short8;
typedef __attribute__((ext_vector_type(4))) short s16x4;
typedef __attribute__((ext_vector_type(8))) __bf16 bf16x8;

__device__ __forceinline__ float b2f(u16 u){
  union { unsigned int i; float f; } v; v.i = ((unsigned int)u) << 16; return v.f;
}
__device__ __forceinline__ u16 f2b(float f){
  union { float f; unsigned int i; } v; v.f = f;
  unsigned int u = v.i;
  u = u + 0x7FFFu + ((u >> 16) & 1u);   // RNE
  return (u16)(u >> 16);
}
__device__ __forceinline__ f32x4 mfma16(short8 a, short8 b, f32x4 c){
  return __builtin_amdgcn_mfma_f32_16x16x32_bf16(
      __builtin_bit_cast(bf16x8, a), __builtin_bit_cast(bf16x8, b), c, 0, 0, 0);
}
__device__ __forceinline__ void gload16(const void* g, void* l){
  void* gnc = const_cast<void*>(g);
  __builtin_amdgcn_global_load_lds((__attribute__((address_space(1))) void*)gnc,
                                   (__attribute__((address_space(3))) void*)l, 16, 0, 0);
}
__device__ __forceinline__ float max3f(float a, float b, float c){
  return fmaxf(fmaxf(a, b), c);   // folds to v_max3_f32
}

// ---------------- f32 -> bf16 weight conversion -----------------------------
__global__ __launch_bounds__(256) void cvt_k(const float* __restrict__ in,
                                             u16* __restrict__ out, int n4)
{
  int i = blockIdx.x*256 + threadIdx.x;
  if (i < n4){
    float4 v = *(const float4*)(in + (size_t)i*4);
    s16x4 o; o[0]=(short)f2b(v.x); o[1]=(short)f2b(v.y);
    o[2]=(short)f2b(v.z); o[3]=(short)f2b(v.w);
    *(s16x4*)(out + (size_t)i*4) = o;
  }
}

// ---------------- key-bias precompute + vmean zero --------------------------
__global__ __launch_bounds__(256) void kbias_k(const int* __restrict__ mask,
                                               float* __restrict__ kb,
                                               float* __restrict__ vm, int n)
{
  int i = blockIdx.x*256 + threadIdx.x;
  if (i < n) kb[i] = mask[i] ? 0.f : -1e30f;
  if (i < 24*64) vm[i] = 0.f;
}

// ---------------- adaLN modulation: mod[b][6*768] = c @ Wada^T + bada --------
__global__ __launch_bounds__(256) void mod_k(const float* __restrict__ c,
    const float* __restrict__ Wada, const float* __restrict__ bada, float* __restrict__ modb)
{
  int o = blockIdx.x*4 + (threadIdx.x >> 6);   // 0..9215
  int l = threadIdx.x & 63;
  int b = o / 4608, j = o - b*4608;
  const float* cp = c + b*768;
  const float* wp = Wada + (size_t)j*768;
  float s = 0.f;
  for (int k = l; k < 768; k += 64) s += cp[k] * wp[k];
  #pragma unroll
  for (int d=1; d<64; d<<=1) s += __shfl_xor(s, d);
  if (l == 0) modb[o] = s + bada[j];
}

// ---------------- LayerNorm (no affine) * w * (1+scale) + shift -> bf16 -----
__global__ __launch_bounds__(256) void ln_mod_k(const float* __restrict__ xin,
    u16* __restrict__ out, const float* __restrict__ lnw, const float* __restrict__ modb,
    int shift_c, int scale_c)
{
  int row = blockIdx.x;             // 0..8191 (b*4096+s)
  int b = row >> 12;
  const float* xp = xin + (size_t)row*768;
  int t = threadIdx.x;
  float v[3]; float s = 0.f, s2 = 0.f;
  #pragma unroll
  for (int i=0;i<3;i++){ float f = xp[t + i*256]; v[i] = f; s += f; s2 += f*f; }
  #pragma unroll
  for (int d=1; d<64; d<<=1){ s += __shfl_xor(s, d); s2 += __shfl_xor(s2, d); }
  __shared__ float rs_[4], rs2_[4];
  int w = t >> 6;
  if ((t & 63) == 0){ rs_[w] = s; rs2_[w] = s2; }
  __syncthreads();
  s  = rs_[0]+rs_[1]+rs_[2]+rs_[3];
  s2 = rs2_[0]+rs2_[1]+rs2_[2]+rs2_[3];
  float mu  = s * (1.f/768.f);
  float var = fmaxf(s2 * (1.f/768.f) - mu*mu, 0.f);
  float rstd = rsqrtf(var + 1e-5f);
  const float* scp = modb + b*4608 + scale_c*768;
  const float* shp = modb + b*4608 + shift_c*768;
  #pragma unroll
  for (int i=0;i<3;i++){
    int d = t + i*256;
    float f = (v[i]-mu)*rstd*lnw[d];
    f = f*(1.f + scp[d]) + shp[d];
    out[(size_t)row*768 + d] = f2b(f);
  }
}

// ---------------- 128x128 BK=64 GEMM, C = A[M,K] @ Bt[N,K]^T, fused epilogues
// EPI 0: C(bf16)=acc (qkv).     1: C(f32) = x + gate_msa*acc (x1).
// EPI 2: C(bf16)=gelu(acc+b1).  3: C(f32) = x1 + gate_mlp*(acc+b2).
template<int EPI>
__global__ __launch_bounds__(256) void gemm_k(
    const u16* __restrict__ A, const u16* __restrict__ Bt, void* __restrict__ Cv,
    int M, int N, int K,
    const float* __restrict__ addend, const float* __restrict__ modb,
    const float* __restrict__ bias)
{
  __shared__ __align__(16) u16 As[128*64];
  __shared__ __align__(16) u16 Bs[128*64];
  const int bm = blockIdx.x, bn = blockIdx.y;
  const int tid = threadIdx.x;
  const int w = tid >> 6, l = tid & 63;
  const int wr = w >> 1, wc = w & 1;
  const int l15 = l & 15, lg = l >> 4;
  f32x4 acc[4][4] = {};

  for (int k0 = 0; k0 < K; k0 += 64){
    #pragma unroll
    for (int i=0;i<4;i++){
      int e = i*256 + tid;
      int r = e >> 3, ch = e & 7;
      int sc = ch ^ (r & 7);
      gload16(A  + (size_t)(bm*128 + r)*K + k0 + sc*8, &As[e*8]);
      gload16(Bt + (size_t)(bn*128 + r)*K + k0 + sc*8, &Bs[e*8]);
    }
    __syncthreads();
    #pragma unroll
    for (int kk=0;kk<2;kk++){
      short8 af[4], bfv[4];
      #pragma unroll
      for (int i=0;i<4;i++){
        int ra = wr*64 + i*16 + l15;
        af[i]  = *(const short8*)&As[ra*64 + (((kk*4)+lg) ^ (ra&7))*8];
        int rb = wc*64 + i*16 + l15;
        bfv[i] = *(const short8*)&Bs[rb*64 + (((kk*4)+lg) ^ (rb&7))*8];
      }
      #pragma unroll
      for (int m=0;m<4;m++)
        #pragma unroll
        for (int n=0;n<4;n++)
          acc[m][n] = mfma16(af[m], bfv[n], acc[m][n]);
    }
    __syncthreads();
  }

  #pragma unroll
  for (int m=0;m<4;m++){
    int row0 = bm*128 + wr*64 + m*16 + lg*4;
    #pragma unroll
    for (int n=0;n<4;n++){
      int col = bn*128 + wc*64 + n*16 + l15;
      #pragma unroll
      for (int r=0;r<4;r++){
        int row = row0 + r;
        size_t idx = (size_t)row*N + col;
        float v = acc[m][n][r];
        if constexpr (EPI == 0){
          ((u16*)Cv)[idx] = f2b(v);
        } else if constexpr (EPI == 1){
          float g = modb[(row>>12)*4608 + 2*768 + col];   // gate_msa
          ((float*)Cv)[idx] = addend[idx] + g*v;
        } else if constexpr (EPI == 2){
          float u = v + bias[col];
          float t0 = 0.7978845608028654f*(u + 0.044715f*u*u*u);
          ((u16*)Cv)[idx] = f2b(0.5f*u*(1.0f + tanhf(t0)));
        } else {
          float g = modb[(row>>12)*4608 + 5*768 + col];   // gate_mlp
          float u = v + bias[col];
          ((float*)Cv)[idx] = addend[idx] + g*u;
        }
      }
    }
  }
}

// ---------------- RoPE on q,k,v + relayout to [b*h][s][64] (bf16) -----------
// q additionally scaled by 0.125*log2(e) so attention works in log2 domain.
__global__ __launch_bounds__(256) void rope_k(const u16* __restrict__ qkv,
    const float* __restrict__ cosb, const float* __restrict__ sinb,
    u16* __restrict__ qO, u16* __restrict__ kO, u16* __restrict__ vO)
{
  int row = blockIdx.x;
  int b = row >> 12, s = row & 4095;
  const u16* qp = qkv + (size_t)row*2304;
  for (int j = threadIdx.x; j < 576; j += 256){
    int inst = j >> 4;          // 0..35 = qkv_idx*12 + h
    int p2 = (j & 15)*2;        // d in [0,32) step 2
    int col0 = inst*64 + p2;
    float a0 = b2f(qp[col0]),     a1 = b2f(qp[col0+1]);
    float bb0 = b2f(qp[col0+32]), bb1 = b2f(qp[col0+33]);
    float c0 = cosb[s*64+p2],    c1 = cosb[s*64+p2+1];
    float c2 = cosb[s*64+p2+32], c3 = cosb[s*64+p2+33];
    float s0 = sinb[s*64+p2],    s1 = sinb[s*64+p2+1];
    float s2 = sinb[s*64+p2+32], s3 = sinb[s*64+p2+33];
    int qi = inst / 12, h = inst - qi*12;
    float qs = (qi == 0) ? 0.1803368801111601f : 1.f;  // 0.125*log2(e)
    u16* dst = (qi == 0) ? qO : (qi == 1) ? kO : vO;
    size_t base = ((size_t)(b*12 + h)*4096 + s)*64;
    dst[base + p2]      = f2b((a0*c0 - bb0*s0)*qs);
    dst[base + p2 + 1]  = f2b((a1*c1 - bb1*s1)*qs);
    dst[base + p2 + 32] = f2b((bb0*c2 + a0*s2)*qs);
    dst[base + p2 + 33] = f2b((bb1*c3 + a1*s3)*qs);
  }
}

// ---------------- V transpose + column-sum atomics --------------------------
__global__ __launch_bounds__(256) void vtr_k(const u16* __restrict__ vS,
                                             u16* __restrict__ vT,
                                             float* __restrict__ vm)
{
  __shared__ __align__(16) u16 tile[64][72];
  __shared__ float cs[4][64];
  int st = blockIdx.x, bh = blockIdx.y;
  int t = threadIdx.x;
  #pragma unroll
  for (int i=0;i<2;i++){
    int e = i*256 + t;
    int r = e >> 3, d0 = (e & 7)*8;
    short8 vv = *(const short8*)(vS + ((size_t)bh*4096 + st*64 + r)*64 + d0);
    *(short8*)&tile[r][d0] = vv;
  }
  __syncthreads();
  #pragma unroll
  for (int i=0;i<2;i++){
    int e = i*256 + t;
    int d = e >> 3, s0 = (e & 7)*8;
    short8 ov;
    #pragma unroll
    for (int k2=0;k2<8;k2++) ov[k2] = (short)tile[s0+k2][d];
    *(short8*)(vT + ((size_t)bh*64 + d)*4096 + st*64 + s0) = ov;
  }
  // column sums of this 64x64 tile -> atomic accumulate
  int d = t & 63, qq = t >> 6;
  float s = 0.f;
  #pragma unroll
  for (int i=0;i<16;i++) s += b2f(tile[qq*16 + i][d]);
  cs[qq][d] = s;
  __syncthreads();
  if (qq == 0) atomicAdd(&vm[bh*64 + d], cs[0][d]+cs[1][d]+cs[2][d]+cs[3][d]);
}

// ---------------- flash attention v6: staggered counted vmcnt ---------------
// Per-body VMEM issue order (per thread): [K-gload, kb x4, V-gload] = 6.
// Steady-state queue = 12; waits: vmcnt(11) before QK^T, vmcnt(7) before
// softmax, vmcnt(6) before PV. Raw barrier at body end, no drain.
#define AT_BODY(KT, PAR, STC, STN, KBC, KBN)                                   \
{                                                                              \
  { int k2 = (KT)+2 < 64 ? (KT)+2 : 63;                                        \
    gload16(kbase + (size_t)(k2*64+sr)*64 + ssc*8, &Ks[PAR][tid*8]); }         \
  {                                                                            \
    int ki = (KT)+1 < 64 ? (KT)+1 : 63;                                        \
    _Pragma("unroll")                                                          \
    for (int n=0;n<4;n++)                                                      \
      KBN[n] = *(const f32x4*)(kbrow + ki*64 + n*16 + lg*4);                   \
  }                                                                            \
  { int vv = (KT)+1 < 64 ? (KT)+1 : 63;                                        \
    gload16(vbase + (size_t)sr*4096 + vv*64 + ssc*8, &Vs[(PAR)^1][tid*8]); }   \
  asm volatile("s_waitcnt vmcnt(11)" ::: "memory");                            \
  if ((KT)+1 < 64){                                                            \
    __builtin_amdgcn_s_setprio(1);                                             \
    _Pragma("unroll")                                                          \
    for (int n=0;n<4;n++){                                                     \
      int R = n*16 + l15;                                                      \
      f32x4 a_ = {};                                                           \
      _Pragma("unroll")                                                        \
      for (int kk=0;kk<2;kk++){                                                \
        short8 ka = *(const short8*)&Ks[(PAR)^1][R*64 + (((kk<<2)+lg) ^ (R&7))*8]; \
        a_ = mfma16(ka, bq[kk], a_);                                           \
      }                                                                        \
      STN[n] = a_;                                                             \
    }                                                                          \
    __builtin_amdgcn_s_setprio(0);                                             \
  }                                                                            \
  asm volatile("s_waitcnt vmcnt(7)" ::: "memory");                             \
  float p_[4][4];                                                              \
  _Pragma("unroll")                                                            \
  for (int n=0;n<4;n++)                                                        \
    _Pragma("unroll")                                                          \
    for (int r=0;r<4;r++) p_[n][r] = STC[n][r] + KBC[n][r];                    \
  float m0_ = max3f(p_[0][0], p_[0][1], p_[0][2]);                             \
  float m1_ = max3f(p_[0][3], p_[1][0], p_[1][1]);                             \
  float m2_ = max3f(p_[1][2], p_[1][3], p_[2][0]);                             \
  float m3_ = max3f(p_[2][1], p_[2][2], p_[2][3]);                             \
  float m4_ = max3f(p_[3][0], p_[3][1], p_[3][2]);                             \
  float pm_ = fmaxf(max3f(m0_, m1_, m2_), max3f(m3_, m4_, p_[3][3]));          \
  pm_ = fmaxf(pm_, __shfl_xor(pm_, 16));                                       \
  pm_ = fmaxf(pm_, __shfl_xor(pm_, 32));                                       \
  if (__any(pm_ > m_run + 8.f)){                                               \
    float mn_ = fmaxf(m_run, pm_);                                             \
    float al_ = __builtin_amdgcn_exp2f(m_run - mn_);                           \
    l_run *= al_;                                                              \
    _Pragma("unroll")                                                          \
    for (int n=0;n<4;n++) oacc[n] *= al_;                                      \
    m_run = mn_;                                                               \
  }                                                                            \
  float ts_ = 0.f;                                                             \
  _Pragma("unroll")                                                            \
  for (int n=0;n<4;n++)                                                        \
    _Pragma("unroll")                                                          \
    for (int r=0;r<4;r++){                                                     \
      float e_ = __builtin_amdgcn_exp2f(p_[n][r] - m_run);                     \
      p_[n][r] = e_; ts_ += e_;                                                \
    }                                                                          \
  ts_ += __shfl_xor(ts_, 16);                                                  \
  ts_ += __shfl_xor(ts_, 32);                                                  \
  l_run += ts_;                                                                \
  _Pragma("unroll")                                                            \
  for (int n=0;n<4;n++){                                                       \
    unsigned p01_, p23_;                                                       \
    asm("v_cvt_pk_bf16_f32 %0, %1, %2" : "=v"(p01_) : "v"(p_[n][0]), "v"(p_[n][1])); \
    asm("v_cvt_pk_bf16_f32 %0, %1, %2" : "=v"(p23_) : "v"(p_[n][2]), "v"(p_[n][3])); \
    int s0_ = n*16 + lg*4;                                                     \
    int off_ = (((s0_>>3) ^ (l15&7))<<3) + (s0_&7);                            \
    *(unsigned*)&Ps[w][l15*64 + off_]     = p01_;                              \
    *(unsigned*)&Ps[w][l15*64 + off_ + 2] = p23_;                              \
  }                                                                            \
  asm volatile("s_waitcnt vmcnt(6)" ::: "memory");                             \
  __builtin_amdgcn_s_setprio(1);                                               \
  _Pragma("unroll")                                                            \
  for (int kk=0;kk<2;kk++){                                                    \
    int ch_ = (kk<<2) + lg;                                                    \
    short8 bp_ = *(const short8*)&Ps[w][l15*64 + ((ch_ ^ (l15&7))<<3)];        \
    _Pragma("unroll")                                                          \
    for (int n=0;n<4;n++){                                                     \
      int R = n*16 + l15;                                                      \
      short8 va_ = *(const short8*)&Vs[PAR][R*64 + ((ch_ ^ (R&7))<<3)];        \
      oacc[n] = mfma16(va_, bp_, oacc[n]);                                     \
    }                                                                          \
  }                                                                            \
  __builtin_amdgcn_s_setprio(0);                                               \
  __builtin_amdgcn_s_barrier();                                                \
}

__global__ __launch_bounds__(512) void attn_k(
    const u16* __restrict__ qT, const u16* __restrict__ kT, const u16* __restrict__ vT,
    const int* __restrict__ mask, const float* __restrict__ kbias,
    const float* __restrict__ vmean, u16* __restrict__ o)
{
  __shared__ __align__(16) u16 Ks[2][64*64];
  __shared__ __align__(16) u16 Vs[2][64*64];
  __shared__ __align__(16) u16 Ps[8][16*64];
  const int qt = blockIdx.x, bh = blockIdx.y;
  const int b = bh / 12, h = bh - b*12;
  const int tid = threadIdx.x, w = tid >> 6, l = tid & 63;
  const int l15 = l & 15, lg = l >> 4;

  short8 bq[2];
  {
    const u16* qp = qT + ((size_t)bh*4096 + qt*128 + w*16 + l15)*64 + lg*8;
    bq[0] = *(const short8*)qp;
    bq[1] = *(const short8*)(qp + 32);
  }
  const bool fq = mask[b*4096 + qt*128 + w*16 + l15] != 0;
  const float* kbrow = kbias + b*4096;
  const u16* kbase = kT + (size_t)bh*4096*64;
  const u16* vbase = vT + (size_t)bh*64*4096;

  float m_run = -1e4f, l_run = 0.f;
  f32x4 oacc[4] = {};   // O^T[d = n*16+lg*4+r][q = l15]

  const int sr = tid >> 3, ssc = (tid & 7) ^ (sr & 7);

  // prologue: stage K0,V0,K1; load kb(0); full drain; QK^T(0)
  f32x4 kbA[4], kbB[4];
  #pragma unroll
  for (int n=0;n<4;n++) kbA[n] = *(const f32x4*)(kbrow + n*16 + lg*4);
  gload16(kbase + (size_t)sr*64 + ssc*8, &Ks[0][tid*8]);
  gload16(vbase + (size_t)sr*4096 + ssc*8, &Vs[0][tid*8]);
  gload16(kbase + (size_t)(64+sr)*64 + ssc*8, &Ks[1][tid*8]);
  asm volatile("s_waitcnt vmcnt(0)" ::: "memory");
  __builtin_amdgcn_s_barrier();

  f32x4 stA[4], stB[4];
  #pragma unroll
  for (int n=0;n<4;n++){
    int R = n*16 + l15;
    f32x4 a_ = {};
    #pragma unroll
    for (int kk=0;kk<2;kk++){
      short8 ka = *(const short8*)&Ks[0][R*64 + (((kk<<2)+lg) ^ (R&7))*8];
      a_ = mfma16(ka, bq[kk], a_);
    }
    stA[n] = a_;
  }
  __builtin_amdgcn_s_barrier();   // all waves done reading Ks[0] before body(0) restages it

  for (int kt = 0; kt < 64; kt += 2){
    AT_BODY(kt,   0, stA, stB, kbA, kbB)
    AT_BODY(kt+1, 1, stB, stA, kbB, kbA)
  }

  float inv = 1.f / l_run;
  size_t base = ((size_t)b*4096 + qt*128 + w*16 + l15)*768 + h*64 + lg*4;
  #pragma unroll
  for (int n=0;n<4;n++){
    f32x4 vm = *(const f32x4*)(vmean + bh*64 + n*16 + lg*4);
    float v0 = fq ? oacc[n][0]*inv : vm[0]*(1.f/4096.f);
    float v1 = fq ? oacc[n][1]*inv : vm[1]*(1.f/4096.f);
    float v2 = fq ? oacc[n][2]*inv : vm[2]*(1.f/4096.f);
    float v3 = fq ? oacc[n][3]*inv : vm[3]*(1.f/4096.f);
    unsigned q01 = (unsigned)f2b(v0) | ((unsigned)f2b(v1) << 16);
    unsigned q23 = (unsigned)f2b(v2) | ((unsigned)f2b(v3) << 16);
    *(unsigned*)&o[base + n*16]     = q01;
    *(unsigned*)&o[base + n*16 + 2] = q23;
  }
}

// ---------------------------------------------------------------------------
extern "C" void kernel_launch(void* const* d_in, const int* in_sizes, int n_in,
                              void* d_out, int out_size, void* d_ws, size_t ws_size,
                              hipStream_t stream)
{
  const float* x    = (const float*)d_in[0];
  const float* cosb = (const float*)d_in[1];
  const float* sinb = (const float*)d_in[2];
  const float* c    = (const float*)d_in[3];
  const int* amask  = (const int*)d_in[4];
  const float* ln1w = (const float*)d_in[5];
  const float* Wqkv = (const float*)d_in[6];
  const float* Wout = (const float*)d_in[7];
  const float* ln2w = (const float*)d_in[8];
  const float* W1   = (const float*)d_in[9];
  const float* b1   = (const float*)d_in[10];
  const float* W2   = (const float*)d_in[11];
  const float* b2   = (const float*)d_in[12];
  const float* Wada = (const float*)d_in[13];
  const float* bada = (const float*)d_in[14];

  char* ws = (char*)d_ws;
  size_t off = 0;
  auto take = [&](size_t bytes)->char*{
    char* p = ws + off; off = (off + bytes + 255) & ~(size_t)255; return p;
  };
  float* modb = (float*)take(9216*sizeof(float));
  float* kbias= (float*)take(8192*sizeof(float));
  float* vmean= (float*)take(24*64*sizeof(float));
  u16* hdn  = (u16*)take((size_t)8192*768*2);    // hdn, then h2 (bf16)
  u16* bufA = (u16*)take((size_t)8192*3072*2);   // qkv raw, then MLP mid (bf16)
  u16* vS   = (u16*)take((size_t)8192*768*2);    // v (s-major)
  u16* qTb  = (u16*)take((size_t)8192*768*2);
  u16* kTb  = (u16*)take((size_t)8192*768*2);
  u16* vTb  = (u16*)take((size_t)8192*768*2);    // v (d-major)
  u16* ob   = (u16*)take((size_t)8192*768*2);    // attention output (bf16)
  u16* WqkvB= (u16*)take((size_t)2304*768*2);
  u16* WoutB= (u16*)take((size_t)768*768*2);
  u16* W1B  = (u16*)take((size_t)3072*768*2);
  u16* W2B  = (u16*)take((size_t)768*3072*2);
  float* out = (float*)d_out;
  float* x1 = out;                               // reuse d_out for x1 (f32)

  cvt_k<<<(2304*768/4+255)/256, 256, 0, stream>>>(Wqkv, WqkvB, 2304*768/4);
  cvt_k<<<(768*768/4+255)/256, 256, 0, stream>>>(Wout, WoutB, 768*768/4);
  cvt_k<<<(3072*768/4+255)/256, 256, 0, stream>>>(W1, W1B, 3072*768/4);
  cvt_k<<<(768*3072/4+255)/256, 256, 0, stream>>>(W2, W2B, 768*3072/4);
  kbias_k<<<32, 256, 0, stream>>>(amask, kbias, vmean, 8192);

  mod_k  <<<2304, 256, 0, stream>>>(c, Wada, bada, modb);
  ln_mod_k<<<8192, 256, 0, stream>>>(x, hdn, ln1w, modb, 0, 1);
  gemm_k<0><<<dim3(64,18), 256, 0, stream>>>(hdn, WqkvB, bufA, 8192, 2304, 768,
                                             nullptr, nullptr, nullptr);
  rope_k <<<8192, 256, 0, stream>>>(bufA, cosb, sinb, qTb, kTb, vS);
  vtr_k  <<<dim3(64,24), 256, 0, stream>>>(vS, vTb, vmean);
  attn_k <<<dim3(32,24), 512, 0, stream>>>(qTb, kTb, vTb, amask, kbias, vmean, ob);
  gemm_k<1><<<dim3(64,6), 256, 0, stream>>>(ob, WoutB, x1, 8192, 768, 768,
                                            x, modb, nullptr);
  ln_mod_k<<<8192, 256, 0, stream>>>(x1, hdn, ln2w, modb, 3, 4);
  gemm_k<2><<<dim3(64,24), 256, 0, stream>>>(hdn, W1B, bufA, 8192, 3072, 768,
                                             nullptr, nullptr, b1);
  gemm_k<3><<<dim3(64,6), 256, 0, stream>>>(bufA, W2B, out, 8192, 768, 3072,
                                            x1, modb, b2);
}

// Round 10
// 414.695 us; speedup vs baseline: 1.1467x; 1.1467x over previous
//
#include <hip/hip_runtime.h>
#include <stdint.h>

// f32 I/O, bf16 MFMA internals. Attention v7: swapped QK^T, QBLK=128 (8
// waves), cross-tile pipeline QK^T(kt+1) || softmax(kt) || PV(kt), with
// FIXED-SHIFT log2 softmax: p = exp2(s + kb), kb in {-32, -1e30}. s is
// bounded (|s| <= 0.18*||q||*||k|| << 32) so no online max / rescale needed;
// softmax weights identical to reference up to f32 rounding. kb loads are
// issued FIRST in each body so the compiler's kb-wait leaves K/V in flight.
// End-of-body vmcnt(0)+barrier = cross-wave-safe publication (race-free).
// Masked-q rows = mean(V) (reference's -1e9 bias absorbs scores in f32).

typedef unsigned short u16;
typedef __attribute__((ext_vector_type(4))) float f32x4;
typedef __attribute__((ext_vector_type(8))) short short8;
typedef __attribute__((ext_vector_type(4))) short s16x4;
typedef __attribute__((ext_vector_type(8))) __bf16 bf16x8;

__device__ __forceinline__ float b2f(u16 u){
  union { unsigned int i; float f; } v; v.i = ((unsigned int)u) << 16; return v.f;
}
__device__ __forceinline__ u16 f2b(float f){
  union { float f; unsigned int i; } v; v.f = f;
  unsigned int u = v.i;
  u = u + 0x7FFFu + ((u >> 16) & 1u);   // RNE
  return (u16)(u >> 16);
}
__device__ __forceinline__ f32x4 mfma16(short8 a, short8 b, f32x4 c){
  return __builtin_amdgcn_mfma_f32_16x16x32_bf16(
      __builtin_bit_cast(bf16x8, a), __builtin_bit_cast(bf16x8, b), c, 0, 0, 0);
}
__device__ __forceinline__ void gload16(const void* g, void* l){
  void* gnc = const_cast<void*>(g);
  __builtin_amdgcn_global_load_lds((__attribute__((address_space(1))) void*)gnc,
                                   (__attribute__((address_space(3))) void*)l, 16, 0, 0);
}

// ---------------- f32 -> bf16 weight conversion -----------------------------
__global__ __launch_bounds__(256) void cvt_k(const float* __restrict__ in,
                                             u16* __restrict__ out, int n4)
{
  int i = blockIdx.x*256 + threadIdx.x;
  if (i < n4){
    float4 v = *(const float4*)(in + (size_t)i*4);
    s16x4 o; o[0]=(short)f2b(v.x); o[1]=(short)f2b(v.y);
    o[2]=(short)f2b(v.z); o[3]=(short)f2b(v.w);
    *(s16x4*)(out + (size_t)i*4) = o;
  }
}

// ------- key-bias precompute (fixed shift baked in) + vmean zero ------------
__global__ __launch_bounds__(256) void kbias_k(const int* __restrict__ mask,
                                               float* __restrict__ kb,
                                               float* __restrict__ vm, int n)
{
  int i = blockIdx.x*256 + threadIdx.x;
  if (i < n) kb[i] = mask[i] ? -32.f : -1e30f;
  if (i < 24*64) vm[i] = 0.f;
}

// ---------------- adaLN modulation: mod[b][6*768] = c @ Wada^T + bada --------
__global__ __launch_bounds__(256) void mod_k(const float* __restrict__ c,
    const float* __restrict__ Wada, const float* __restrict__ bada, float* __restrict__ modb)
{
  int o = blockIdx.x*4 + (threadIdx.x >> 6);   // 0..9215
  int l = threadIdx.x & 63;
  int b = o / 4608, j = o - b*4608;
  const float* cp = c + b*768;
  const float* wp = Wada + (size_t)j*768;
  float s = 0.f;
  for (int k = l; k < 768; k += 64) s += cp[k] * wp[k];
  #pragma unroll
  for (int d=1; d<64; d<<=1) s += __shfl_xor(s, d);
  if (l == 0) modb[o] = s + bada[j];
}

// ---------------- LayerNorm (no affine) * w * (1+scale) + shift -> bf16 -----
__global__ __launch_bounds__(256) void ln_mod_k(const float* __restrict__ xin,
    u16* __restrict__ out, const float* __restrict__ lnw, const float* __restrict__ modb,
    int shift_c, int scale_c)
{
  int row = blockIdx.x;             // 0..8191 (b*4096+s)
  int b = row >> 12;
  const float* xp = xin + (size_t)row*768;
  int t = threadIdx.x;
  float v[3]; float s = 0.f, s2 = 0.f;
  #pragma unroll
  for (int i=0;i<3;i++){ float f = xp[t + i*256]; v[i] = f; s += f; s2 += f*f; }
  #pragma unroll
  for (int d=1; d<64; d<<=1){ s += __shfl_xor(s, d); s2 += __shfl_xor(s2, d); }
  __shared__ float rs_[4], rs2_[4];
  int w = t >> 6;
  if ((t & 63) == 0){ rs_[w] = s; rs2_[w] = s2; }
  __syncthreads();
  s  = rs_[0]+rs_[1]+rs_[2]+rs_[3];
  s2 = rs2_[0]+rs2_[1]+rs2_[2]+rs2_[3];
  float mu  = s * (1.f/768.f);
  float var = fmaxf(s2 * (1.f/768.f) - mu*mu, 0.f);
  float rstd = rsqrtf(var + 1e-5f);
  const float* scp = modb + b*4608 + scale_c*768;
  const float* shp = modb + b*4608 + shift_c*768;
  #pragma unroll
  for (int i=0;i<3;i++){
    int d = t + i*256;
    float f = (v[i]-mu)*rstd*lnw[d];
    f = f*(1.f + scp[d]) + shp[d];
    out[(size_t)row*768 + d] = f2b(f);
  }
}

// ---------------- 128x128 BK=64 GEMM, C = A[M,K] @ Bt[N,K]^T, fused epilogues
// EPI 0: C(bf16)=acc (qkv).     1: C(f32) = x + gate_msa*acc (x1).
// EPI 2: C(bf16)=gelu(acc+b1).  3: C(f32) = x1 + gate_mlp*(acc+b2).
template<int EPI>
__global__ __launch_bounds__(256) void gemm_k(
    const u16* __restrict__ A, const u16* __restrict__ Bt, void* __restrict__ Cv,
    int M, int N, int K,
    const float* __restrict__ addend, const float* __restrict__ modb,
    const float* __restrict__ bias)
{
  __shared__ __align__(16) u16 As[128*64];
  __shared__ __align__(16) u16 Bs[128*64];
  const int bm = blockIdx.x, bn = blockIdx.y;
  const int tid = threadIdx.x;
  const int w = tid >> 6, l = tid & 63;
  const int wr = w >> 1, wc = w & 1;
  const int l15 = l & 15, lg = l >> 4;
  f32x4 acc[4][4] = {};

  for (int k0 = 0; k0 < K; k0 += 64){
    #pragma unroll
    for (int i=0;i<4;i++){
      int e = i*256 + tid;
      int r = e >> 3, ch = e & 7;
      int sc = ch ^ (r & 7);
      gload16(A  + (size_t)(bm*128 + r)*K + k0 + sc*8, &As[e*8]);
      gload16(Bt + (size_t)(bn*128 + r)*K + k0 + sc*8, &Bs[e*8]);
    }
    __syncthreads();
    #pragma unroll
    for (int kk=0;kk<2;kk++){
      short8 af[4], bfv[4];
      #pragma unroll
      for (int i=0;i<4;i++){
        int ra = wr*64 + i*16 + l15;
        af[i]  = *(const short8*)&As[ra*64 + (((kk*4)+lg) ^ (ra&7))*8];
        int rb = wc*64 + i*16 + l15;
        bfv[i] = *(const short8*)&Bs[rb*64 + (((kk*4)+lg) ^ (rb&7))*8];
      }
      #pragma unroll
      for (int m=0;m<4;m++)
        #pragma unroll
        for (int n=0;n<4;n++)
          acc[m][n] = mfma16(af[m], bfv[n], acc[m][n]);
    }
    __syncthreads();
  }

  #pragma unroll
  for (int m=0;m<4;m++){
    int row0 = bm*128 + wr*64 + m*16 + lg*4;
    #pragma unroll
    for (int n=0;n<4;n++){
      int col = bn*128 + wc*64 + n*16 + l15;
      #pragma unroll
      for (int r=0;r<4;r++){
        int row = row0 + r;
        size_t idx = (size_t)row*N + col;
        float v = acc[m][n][r];
        if constexpr (EPI == 0){
          ((u16*)Cv)[idx] = f2b(v);
        } else if constexpr (EPI == 1){
          float g = modb[(row>>12)*4608 + 2*768 + col];   // gate_msa
          ((float*)Cv)[idx] = addend[idx] + g*v;
        } else if constexpr (EPI == 2){
          float u = v + bias[col];
          float t0 = 0.7978845608028654f*(u + 0.044715f*u*u*u);
          ((u16*)Cv)[idx] = f2b(0.5f*u*(1.0f + tanhf(t0)));
        } else {
          float g = modb[(row>>12)*4608 + 5*768 + col];   // gate_mlp
          float u = v + bias[col];
          ((float*)Cv)[idx] = addend[idx] + g*u;
        }
      }
    }
  }
}

// ---------------- RoPE on q,k,v + relayout to [b*h][s][64] (bf16) -----------
// q additionally scaled by 0.125*log2(e) so attention works in log2 domain.
__global__ __launch_bounds__(256) void rope_k(const u16* __restrict__ qkv,
    const float* __restrict__ cosb, const float* __restrict__ sinb,
    u16* __restrict__ qO, u16* __restrict__ kO, u16* __restrict__ vO)
{
  int row = blockIdx.x;
  int b = row >> 12, s = row & 4095;
  const u16* qp = qkv + (size_t)row*2304;
  for (int j = threadIdx.x; j < 576; j += 256){
    int inst = j >> 4;          // 0..35 = qkv_idx*12 + h
    int p2 = (j & 15)*2;        // d in [0,32) step 2
    int col0 = inst*64 + p2;
    float a0 = b2f(qp[col0]),     a1 = b2f(qp[col0+1]);
    float bb0 = b2f(qp[col0+32]), bb1 = b2f(qp[col0+33]);
    float c0 = cosb[s*64+p2],    c1 = cosb[s*64+p2+1];
    float c2 = cosb[s*64+p2+32], c3 = cosb[s*64+p2+33];
    float s0 = sinb[s*64+p2],    s1 = sinb[s*64+p2+1];
    float s2 = sinb[s*64+p2+32], s3 = sinb[s*64+p2+33];
    int qi = inst / 12, h = inst - qi*12;
    float qs = (qi == 0) ? 0.1803368801111601f : 1.f;  // 0.125*log2(e)
    u16* dst = (qi == 0) ? qO : (qi == 1) ? kO : vO;
    size_t base = ((size_t)(b*12 + h)*4096 + s)*64;
    dst[base + p2]      = f2b((a0*c0 - bb0*s0)*qs);
    dst[base + p2 + 1]  = f2b((a1*c1 - bb1*s1)*qs);
    dst[base + p2 + 32] = f2b((bb0*c2 + a0*s2)*qs);
    dst[base + p2 + 33] = f2b((bb1*c3 + a1*s3)*qs);
  }
}

// ---------------- V transpose + column-sum atomics --------------------------
__global__ __launch_bounds__(256) void vtr_k(const u16* __restrict__ vS,
                                             u16* __restrict__ vT,
                                             float* __restrict__ vm)
{
  __shared__ __align__(16) u16 tile[64][72];
  __shared__ float cs[4][64];
  int st = blockIdx.x, bh = blockIdx.y;
  int t = threadIdx.x;
  #pragma unroll
  for (int i=0;i<2;i++){
    int e = i*256 + t;
    int r = e >> 3, d0 = (e & 7)*8;
    short8 vv = *(const short8*)(vS + ((size_t)bh*4096 + st*64 + r)*64 + d0);
    *(short8*)&tile[r][d0] = vv;
  }
  __syncthreads();
  #pragma unroll
  for (int i=0;i<2;i++){
    int e = i*256 + t;
    int d = e >> 3, s0 = (e & 7)*8;
    short8 ov;
    #pragma unroll
    for (int k2=0;k2<8;k2++) ov[k2] = (short)tile[s0+k2][d];
    *(short8*)(vT + ((size_t)bh*64 + d)*4096 + st*64 + s0) = ov;
  }
  // column sums of this 64x64 tile -> atomic accumulate
  int d = t & 63, qq = t >> 6;
  float s = 0.f;
  #pragma unroll
  for (int i=0;i<16;i++) s += b2f(tile[qq*16 + i][d]);
  cs[qq][d] = s;
  __syncthreads();
  if (qq == 0) atomicAdd(&vm[bh*64 + d], cs[0][d]+cs[1][d]+cs[2][d]+cs[3][d]);
}

// ---------------- flash attention v7: fixed-shift softmax -------------------
#define AT_BODY(KT, PAR, STC, STN)                                             \
{                                                                              \
  f32x4 kb_[4];                                                                \
  _Pragma("unroll")                                                            \
  for (int n=0;n<4;n++)                                                        \
    kb_[n] = *(const f32x4*)(kbrow + (KT)*64 + n*16 + lg*4);                   \
  { int k2 = (KT)+2 < 64 ? (KT)+2 : 63;                                        \
    gload16(kbase + (size_t)(k2*64+sr)*64 + ssc*8, &Ks[PAR][tid*8]); }         \
  { int vv = (KT)+1 < 64 ? (KT)+1 : 63;                                        \
    gload16(vbase + (size_t)sr*4096 + vv*64 + ssc*8, &Vs[(PAR)^1][tid*8]); }   \
  if ((KT)+1 < 64){                                                            \
    __builtin_amdgcn_s_setprio(1);                                             \
    _Pragma("unroll")                                                          \
    for (int n=0;n<4;n++){                                                     \
      int R = n*16 + l15;                                                      \
      f32x4 a_ = {};                                                           \
      _Pragma("unroll")                                                        \
      for (int kk=0;kk<2;kk++){                                                \
        short8 ka = *(const short8*)&Ks[(PAR)^1][R*64 + (((kk<<2)+lg) ^ (R&7))*8]; \
        a_ = mfma16(ka, bq[kk], a_);                                           \
      }                                                                        \
      STN[n] = a_;                                                             \
    }                                                                          \
    __builtin_amdgcn_s_setprio(0);                                             \
  }                                                                            \
  float p_[4][4]; float ts_ = 0.f;                                             \
  _Pragma("unroll")                                                            \
  for (int n=0;n<4;n++)                                                        \
    _Pragma("unroll")                                                          \
    for (int r=0;r<4;r++){                                                     \
      float e_ = __builtin_amdgcn_exp2f(STC[n][r] + kb_[n][r]);                \
      p_[n][r] = e_; ts_ += e_;                                                \
    }                                                                          \
  ts_ += __shfl_xor(ts_, 16);                                                  \
  ts_ += __shfl_xor(ts_, 32);                                                  \
  l_run += ts_;                                                                \
  _Pragma("unroll")                                                            \
  for (int n=0;n<4;n++){                                                       \
    unsigned p01_, p23_;                                                       \
    asm("v_cvt_pk_bf16_f32 %0, %1, %2" : "=v"(p01_) : "v"(p_[n][0]), "v"(p_[n][1])); \
    asm("v_cvt_pk_bf16_f32 %0, %1, %2" : "=v"(p23_) : "v"(p_[n][2]), "v"(p_[n][3])); \
    int s0_ = n*16 + lg*4;                                                     \
    int off_ = (((s0_>>3) ^ (l15&7))<<3) + (s0_&7);                            \
    *(unsigned*)&Ps[w][l15*64 + off_]     = p01_;                              \
    *(unsigned*)&Ps[w][l15*64 + off_ + 2] = p23_;                              \
  }                                                                            \
  __builtin_amdgcn_s_setprio(1);                                               \
  _Pragma("unroll")                                                            \
  for (int kk=0;kk<2;kk++){                                                    \
    int ch_ = (kk<<2) + lg;                                                    \
    short8 bp_ = *(const short8*)&Ps[w][l15*64 + ((ch_ ^ (l15&7))<<3)];        \
    _Pragma("unroll")                                                          \
    for (int n=0;n<4;n++){                                                     \
      int R = n*16 + l15;                                                      \
      short8 va_ = *(const short8*)&Vs[PAR][R*64 + ((ch_ ^ (R&7))<<3)];        \
      oacc[n] = mfma16(va_, bp_, oacc[n]);                                     \
    }                                                                          \
  }                                                                            \
  __builtin_amdgcn_s_setprio(0);                                               \
  asm volatile("s_waitcnt vmcnt(0)" ::: "memory");                             \
  __builtin_amdgcn_s_barrier();                                                \
}

__global__ __launch_bounds__(512) void attn_k(
    const u16* __restrict__ qT, const u16* __restrict__ kT, const u16* __restrict__ vT,
    const int* __restrict__ mask, const float* __restrict__ kbias,
    const float* __restrict__ vmean, u16* __restrict__ o)
{
  __shared__ __align__(16) u16 Ks[2][64*64];
  __shared__ __align__(16) u16 Vs[2][64*64];
  __shared__ __align__(16) u16 Ps[8][16*64];
  const int qt = blockIdx.x, bh = blockIdx.y;
  const int b = bh / 12, h = bh - b*12;
  const int tid = threadIdx.x, w = tid >> 6, l = tid & 63;
  const int l15 = l & 15, lg = l >> 4;

  short8 bq[2];
  {
    const u16* qp = qT + ((size_t)bh*4096 + qt*128 + w*16 + l15)*64 + lg*8;
    bq[0] = *(const short8*)qp;
    bq[1] = *(const short8*)(qp + 32);
  }
  const bool fq = mask[b*4096 + qt*128 + w*16 + l15] != 0;
  const float* kbrow = kbias + b*4096;
  const u16* kbase = kT + (size_t)bh*4096*64;
  const u16* vbase = vT + (size_t)bh*64*4096;

  float l_run = 0.f;
  f32x4 oacc[4] = {};   // O^T[d = n*16+lg*4+r][q = l15]

  const int sr = tid >> 3, ssc = (tid & 7) ^ (sr & 7);

  // prologue: stage K0,V0,K1; drain; QK^T(0)
  gload16(kbase + (size_t)sr*64 + ssc*8, &Ks[0][tid*8]);
  gload16(vbase + (size_t)sr*4096 + ssc*8, &Vs[0][tid*8]);
  gload16(kbase + (size_t)(64+sr)*64 + ssc*8, &Ks[1][tid*8]);
  asm volatile("s_waitcnt vmcnt(0)" ::: "memory");
  __builtin_amdgcn_s_barrier();

  f32x4 stA[4], stB[4];
  #pragma unroll
  for (int n=0;n<4;n++){
    int R = n*16 + l15;
    f32x4 a_ = {};
    #pragma unroll
    for (int kk=0;kk<2;kk++){
      short8 ka = *(const short8*)&Ks[0][R*64 + (((kk<<2)+lg) ^ (R&7))*8];
      a_ = mfma16(ka, bq[kk], a_);
    }
    stA[n] = a_;
  }
  __builtin_amdgcn_s_barrier();   // all waves done reading Ks[0] before body(0) restages it

  for (int kt = 0; kt < 64; kt += 2){
    AT_BODY(kt,   0, stA, stB)
    AT_BODY(kt+1, 1, stB, stA)
  }

  float inv = 1.f / l_run;
  size_t base = ((size_t)b*4096 + qt*128 + w*16 + l15)*768 + h*64 + lg*4;
  #pragma unroll
  for (int n=0;n<4;n++){
    f32x4 vm = *(const f32x4*)(vmean + bh*64 + n*16 + lg*4);
    float v0 = fq ? oacc[n][0]*inv : vm[0]*(1.f/4096.f);
    float v1 = fq ? oacc[n][1]*inv : vm[1]*(1.f/4096.f);
    float v2 = fq ? oacc[n][2]*inv : vm[2]*(1.f/4096.f);
    float v3 = fq ? oacc[n][3]*inv : vm[3]*(1.f/4096.f);
    unsigned q01 = (unsigned)f2b(v0) | ((unsigned)f2b(v1) << 16);
    unsigned q23 = (unsigned)f2b(v2) | ((unsigned)f2b(v3) << 16);
    *(unsigned*)&o[base + n*16]     = q01;
    *(unsigned*)&o[base + n*16 + 2] = q23;
  }
}

// ---------------------------------------------------------------------------
extern "C" void kernel_launch(void* const* d_in, const int* in_sizes, int n_in,
                              void* d_out, int out_size, void* d_ws, size_t ws_size,
                              hipStream_t stream)
{
  const float* x    = (const float*)d_in[0];
  const float* cosb = (const float*)d_in[1];
  const float* sinb = (const float*)d_in[2];
  const float* c    = (const float*)d_in[3];
  const int* amask  = (const int*)d_in[4];
  const float* ln1w = (const float*)d_in[5];
  const float* Wqkv = (const float*)d_in[6];
  const float* Wout = (const float*)d_in[7];
  const float* ln2w = (const float*)d_in[8];
  const float* W1   = (const float*)d_in[9];
  const float* b1   = (const float*)d_in[10];
  const float* W2   = (const float*)d_in[11];
  const float* b2   = (const float*)d_in[12];
  const float* Wada = (const float*)d_in[13];
  const float* bada = (const float*)d_in[14];

  char* ws = (char*)d_ws;
  size_t off = 0;
  auto take = [&](size_t bytes)->char*{
    char* p = ws + off; off = (off + bytes + 255) & ~(size_t)255; return p;
  };
  float* modb = (float*)take(9216*sizeof(float));
  float* kbias= (float*)take(8192*sizeof(float));
  float* vmean= (float*)take(24*64*sizeof(float));
  u16* hdn  = (u16*)take((size_t)8192*768*2);    // hdn, then h2 (bf16)
  u16* bufA = (u16*)take((size_t)8192*3072*2);   // qkv raw, then MLP mid (bf16)
  u16* vS   = (u16*)take((size_t)8192*768*2);    // v (s-major)
  u16* qTb  = (u16*)take((size_t)8192*768*2);
  u16* kTb  = (u16*)take((size_t)8192*768*2);
  u16* vTb  = (u16*)take((size_t)8192*768*2);    // v (d-major)
  u16* ob   = (u16*)take((size_t)8192*768*2);    // attention output (bf16)
  u16* WqkvB= (u16*)take((size_t)2304*768*2);
  u16* WoutB= (u16*)take((size_t)768*768*2);
  u16* W1B  = (u16*)take((size_t)3072*768*2);
  u16* W2B  = (u16*)take((size_t)768*3072*2);
  float* out = (float*)d_out;
  float* x1 = out;                               // reuse d_out for x1 (f32)

  cvt_k<<<(2304*768/4+255)/256, 256, 0, stream>>>(Wqkv, WqkvB, 2304*768/4);
  cvt_k<<<(768*768/4+255)/256, 256, 0, stream>>>(Wout, WoutB, 768*768/4);
  cvt_k<<<(3072*768/4+255)/256, 256, 0, stream>>>(W1, W1B, 3072*768/4);
  cvt_k<<<(768*3072/4+255)/256, 256, 0, stream>>>(W2, W2B, 768*3072/4);
  kbias_k<<<32, 256, 0, stream>>>(amask, kbias, vmean, 8192);

  mod_k  <<<2304, 256, 0, stream>>>(c, Wada, bada, modb);
  ln_mod_k<<<8192, 256, 0, stream>>>(x, hdn, ln1w, modb, 0, 1);
  gemm_k<0><<<dim3(64,18), 256, 0, stream>>>(hdn, WqkvB, bufA, 8192, 2304, 768,
                                             nullptr, nullptr, nullptr);
  rope_k <<<8192, 256, 0, stream>>>(bufA, cosb, sinb, qTb, kTb, vS);
  vtr_k  <<<dim3(64,24), 256, 0, stream>>>(vS, vTb, vmean);
  attn_k <<<dim3(32,24), 512, 0, stream>>>(qTb, kTb, vTb, amask, kbias, vmean, ob);
  gemm_k<1><<<dim3(64,6), 256, 0, stream>>>(ob, WoutB, x1, 8192, 768, 768,
                                            x, modb, nullptr);
  ln_mod_k<<<8192, 256, 0, stream>>>(x1, hdn, ln2w, modb, 3, 4);
  gemm_k<2><<<dim3(64,24), 256, 0, stream>>>(hdn, W1B, bufA, 8192, 3072, 768,
                                             nullptr, nullptr, b1);
  gemm_k<3><<<dim3(64,6), 256, 0, stream>>>(bufA, W2B, out, 8192, 768, 3072,
                                            x1, modb, b2);
}

// Round 11
// 403.002 us; speedup vs baseline: 1.1800x; 1.0290x over previous
//
#include <hip/hip_runtime.h>
#include <stdint.h>

// f32 I/O, bf16 MFMA internals. Attention v8: swapped QK^T, fixed-shift
// log2 softmax (p = exp2(s + kb), kb in {-32,-1e30}), QBLK=128 (8 waves),
// 4-deep K/V LDS rings with prefetch distance 3 (K) / 2 (V). Per-body VMEM
// issue order [kb x4, K, V] pinned by sched_barrier; the compiler's kb-wait
// (vmcnt(2)) retires the previous body's K/V => each tile gets ~2 bodies of
// latency and the barrier needs NO drain. Masked-q rows = mean(V)
// (reference's -1e9 bias absorbs scores in f32 -> uniform attention).

typedef unsigned short u16;
typedef __attribute__((ext_vector_type(4))) float f32x4;
typedef __attribute__((ext_vector_type(8))) short short8;
typedef __attribute__((ext_vector_type(4))) short s16x4;
typedef __attribute__((ext_vector_type(8))) __bf16 bf16x8;

__device__ __forceinline__ float b2f(u16 u){
  union { unsigned int i; float f; } v; v.i = ((unsigned int)u) << 16; return v.f;
}
__device__ __forceinline__ u16 f2b(float f){
  union { float f; unsigned int i; } v; v.f = f;
  unsigned int u = v.i;
  u = u + 0x7FFFu + ((u >> 16) & 1u);   // RNE
  return (u16)(u >> 16);
}
__device__ __forceinline__ f32x4 mfma16(short8 a, short8 b, f32x4 c){
  return __builtin_amdgcn_mfma_f32_16x16x32_bf16(
      __builtin_bit_cast(bf16x8, a), __builtin_bit_cast(bf16x8, b), c, 0, 0, 0);
}
__device__ __forceinline__ void gload16(const void* g, void* l){
  void* gnc = const_cast<void*>(g);
  __builtin_amdgcn_global_load_lds((__attribute__((address_space(1))) void*)gnc,
                                   (__attribute__((address_space(3))) void*)l, 16, 0, 0);
}

// ---------------- f32 -> bf16 weight conversion -----------------------------
__global__ __launch_bounds__(256) void cvt_k(const float* __restrict__ in,
                                             u16* __restrict__ out, int n4)
{
  int i = blockIdx.x*256 + threadIdx.x;
  if (i < n4){
    float4 v = *(const float4*)(in + (size_t)i*4);
    s16x4 o; o[0]=(short)f2b(v.x); o[1]=(short)f2b(v.y);
    o[2]=(short)f2b(v.z); o[3]=(short)f2b(v.w);
    *(s16x4*)(out + (size_t)i*4) = o;
  }
}

// ------- key-bias precompute (fixed shift baked in) + vmean zero ------------
__global__ __launch_bounds__(256) void kbias_k(const int* __restrict__ mask,
                                               float* __restrict__ kb,
                                               float* __restrict__ vm, int n)
{
  int i = blockIdx.x*256 + threadIdx.x;
  if (i < n) kb[i] = mask[i] ? -32.f : -1e30f;
  if (i < 24*64) vm[i] = 0.f;
}

// ---------------- adaLN modulation: mod[b][6*768] = c @ Wada^T + bada --------
__global__ __launch_bounds__(256) void mod_k(const float* __restrict__ c,
    const float* __restrict__ Wada, const float* __restrict__ bada, float* __restrict__ modb)
{
  int o = blockIdx.x*4 + (threadIdx.x >> 6);   // 0..9215
  int l = threadIdx.x & 63;
  int b = o / 4608, j = o - b*4608;
  const float* cp = c + b*768;
  const float* wp = Wada + (size_t)j*768;
  float s = 0.f;
  for (int k = l; k < 768; k += 64) s += cp[k] * wp[k];
  #pragma unroll
  for (int d=1; d<64; d<<=1) s += __shfl_xor(s, d);
  if (l == 0) modb[o] = s + bada[j];
}

// ---------------- LayerNorm (no affine) * w * (1+scale) + shift -> bf16 -----
__global__ __launch_bounds__(256) void ln_mod_k(const float* __restrict__ xin,
    u16* __restrict__ out, const float* __restrict__ lnw, const float* __restrict__ modb,
    int shift_c, int scale_c)
{
  int row = blockIdx.x;             // 0..8191 (b*4096+s)
  int b = row >> 12;
  const float* xp = xin + (size_t)row*768;
  int t = threadIdx.x;
  float v[3]; float s = 0.f, s2 = 0.f;
  #pragma unroll
  for (int i=0;i<3;i++){ float f = xp[t + i*256]; v[i] = f; s += f; s2 += f*f; }
  #pragma unroll
  for (int d=1; d<64; d<<=1){ s += __shfl_xor(s, d); s2 += __shfl_xor(s2, d); }
  __shared__ float rs_[4], rs2_[4];
  int w = t >> 6;
  if ((t & 63) == 0){ rs_[w] = s; rs2_[w] = s2; }
  __syncthreads();
  s  = rs_[0]+rs_[1]+rs_[2]+rs_[3];
  s2 = rs2_[0]+rs2_[1]+rs2_[2]+rs2_[3];
  float mu  = s * (1.f/768.f);
  float var = fmaxf(s2 * (1.f/768.f) - mu*mu, 0.f);
  float rstd = rsqrtf(var + 1e-5f);
  const float* scp = modb + b*4608 + scale_c*768;
  const float* shp = modb + b*4608 + shift_c*768;
  #pragma unroll
  for (int i=0;i<3;i++){
    int d = t + i*256;
    float f = (v[i]-mu)*rstd*lnw[d];
    f = f*(1.f + scp[d]) + shp[d];
    out[(size_t)row*768 + d] = f2b(f);
  }
}

// ---------------- 128x128 BK=64 GEMM, C = A[M,K] @ Bt[N,K]^T, fused epilogues
// EPI 0: C(bf16)=acc (qkv).     1: C(f32) = x + gate_msa*acc (x1).
// EPI 2: C(bf16)=gelu(acc+b1).  3: C(f32) = x1 + gate_mlp*(acc+b2).
template<int EPI>
__global__ __launch_bounds__(256) void gemm_k(
    const u16* __restrict__ A, const u16* __restrict__ Bt, void* __restrict__ Cv,
    int M, int N, int K,
    const float* __restrict__ addend, const float* __restrict__ modb,
    const float* __restrict__ bias)
{
  __shared__ __align__(16) u16 As[128*64];
  __shared__ __align__(16) u16 Bs[128*64];
  const int bm = blockIdx.x, bn = blockIdx.y;
  const int tid = threadIdx.x;
  const int w = tid >> 6, l = tid & 63;
  const int wr = w >> 1, wc = w & 1;
  const int l15 = l & 15, lg = l >> 4;
  f32x4 acc[4][4] = {};

  for (int k0 = 0; k0 < K; k0 += 64){
    #pragma unroll
    for (int i=0;i<4;i++){
      int e = i*256 + tid;
      int r = e >> 3, ch = e & 7;
      int sc = ch ^ (r & 7);
      gload16(A  + (size_t)(bm*128 + r)*K + k0 + sc*8, &As[e*8]);
      gload16(Bt + (size_t)(bn*128 + r)*K + k0 + sc*8, &Bs[e*8]);
    }
    __syncthreads();
    #pragma unroll
    for (int kk=0;kk<2;kk++){
      short8 af[4], bfv[4];
      #pragma unroll
      for (int i=0;i<4;i++){
        int ra = wr*64 + i*16 + l15;
        af[i]  = *(const short8*)&As[ra*64 + (((kk*4)+lg) ^ (ra&7))*8];
        int rb = wc*64 + i*16 + l15;
        bfv[i] = *(const short8*)&Bs[rb*64 + (((kk*4)+lg) ^ (rb&7))*8];
      }
      #pragma unroll
      for (int m=0;m<4;m++)
        #pragma unroll
        for (int n=0;n<4;n++)
          acc[m][n] = mfma16(af[m], bfv[n], acc[m][n]);
    }
    __syncthreads();
  }

  #pragma unroll
  for (int m=0;m<4;m++){
    int row0 = bm*128 + wr*64 + m*16 + lg*4;
    #pragma unroll
    for (int n=0;n<4;n++){
      int col = bn*128 + wc*64 + n*16 + l15;
      #pragma unroll
      for (int r=0;r<4;r++){
        int row = row0 + r;
        size_t idx = (size_t)row*N + col;
        float v = acc[m][n][r];
        if constexpr (EPI == 0){
          ((u16*)Cv)[idx] = f2b(v);
        } else if constexpr (EPI == 1){
          float g = modb[(row>>12)*4608 + 2*768 + col];   // gate_msa
          ((float*)Cv)[idx] = addend[idx] + g*v;
        } else if constexpr (EPI == 2){
          float u = v + bias[col];
          float t0 = 0.7978845608028654f*(u + 0.044715f*u*u*u);
          ((u16*)Cv)[idx] = f2b(0.5f*u*(1.0f + tanhf(t0)));
        } else {
          float g = modb[(row>>12)*4608 + 5*768 + col];   // gate_mlp
          float u = v + bias[col];
          ((float*)Cv)[idx] = addend[idx] + g*u;
        }
      }
    }
  }
}

// ---------------- RoPE on q,k,v + relayout to [b*h][s][64] (bf16) -----------
// q additionally scaled by 0.125*log2(e) so attention works in log2 domain.
__global__ __launch_bounds__(256) void rope_k(const u16* __restrict__ qkv,
    const float* __restrict__ cosb, const float* __restrict__ sinb,
    u16* __restrict__ qO, u16* __restrict__ kO, u16* __restrict__ vO)
{
  int row = blockIdx.x;
  int b = row >> 12, s = row & 4095;
  const u16* qp = qkv + (size_t)row*2304;
  for (int j = threadIdx.x; j < 576; j += 256){
    int inst = j >> 4;          // 0..35 = qkv_idx*12 + h
    int p2 = (j & 15)*2;        // d in [0,32) step 2
    int col0 = inst*64 + p2;
    float a0 = b2f(qp[col0]),     a1 = b2f(qp[col0+1]);
    float bb0 = b2f(qp[col0+32]), bb1 = b2f(qp[col0+33]);
    float c0 = cosb[s*64+p2],    c1 = cosb[s*64+p2+1];
    float c2 = cosb[s*64+p2+32], c3 = cosb[s*64+p2+33];
    float s0 = sinb[s*64+p2],    s1 = sinb[s*64+p2+1];
    float s2 = sinb[s*64+p2+32], s3 = sinb[s*64+p2+33];
    int qi = inst / 12, h = inst - qi*12;
    float qs = (qi == 0) ? 0.1803368801111601f : 1.f;  // 0.125*log2(e)
    u16* dst = (qi == 0) ? qO : (qi == 1) ? kO : vO;
    size_t base = ((size_t)(b*12 + h)*4096 + s)*64;
    dst[base + p2]      = f2b((a0*c0 - bb0*s0)*qs);
    dst[base + p2 + 1]  = f2b((a1*c1 - bb1*s1)*qs);
    dst[base + p2 + 32] = f2b((bb0*c2 + a0*s2)*qs);
    dst[base + p2 + 33] = f2b((bb1*c3 + a1*s3)*qs);
  }
}

// ---------------- V transpose + column-sum atomics --------------------------
__global__ __launch_bounds__(256) void vtr_k(const u16* __restrict__ vS,
                                             u16* __restrict__ vT,
                                             float* __restrict__ vm)
{
  __shared__ __align__(16) u16 tile[64][72];
  __shared__ float cs[4][64];
  int st = blockIdx.x, bh = blockIdx.y;
  int t = threadIdx.x;
  #pragma unroll
  for (int i=0;i<2;i++){
    int e = i*256 + t;
    int r = e >> 3, d0 = (e & 7)*8;
    short8 vv = *(const short8*)(vS + ((size_t)bh*4096 + st*64 + r)*64 + d0);
    *(short8*)&tile[r][d0] = vv;
  }
  __syncthreads();
  #pragma unroll
  for (int i=0;i<2;i++){
    int e = i*256 + t;
    int d = e >> 3, s0 = (e & 7)*8;
    short8 ov;
    #pragma unroll
    for (int k2=0;k2<8;k2++) ov[k2] = (short)tile[s0+k2][d];
    *(short8*)(vT + ((size_t)bh*64 + d)*4096 + st*64 + s0) = ov;
  }
  // column sums of this 64x64 tile -> atomic accumulate
  int d = t & 63, qq = t >> 6;
  float s = 0.f;
  #pragma unroll
  for (int i=0;i<16;i++) s += b2f(tile[qq*16 + i][d]);
  cs[qq][d] = s;
  __syncthreads();
  if (qq == 0) atomicAdd(&vm[bh*64 + d], cs[0][d]+cs[1][d]+cs[2][d]+cs[3][d]);
}

// ---------------- flash attention v8: 4-deep K/V rings ----------------------
// KQK = (KT+1)%4 (QK read), KST = (KT+3)%4 (K stage),
// VPV = KT%4 (PV read),     VST = (KT+2)%4 (V stage).
#define AT_BODY(KT, KQK, KST, VPV, VST, STC, STN)                              \
{                                                                              \
  f32x4 kb_[4];                                                                \
  _Pragma("unroll")                                                            \
  for (int n=0;n<4;n++)                                                        \
    kb_[n] = *(const f32x4*)(kbrow + (KT)*64 + n*16 + lg*4);                   \
  __builtin_amdgcn_sched_barrier(0);  /* pin kb issue before K/V gloads */     \
  { int k3 = (KT)+3 < 64 ? (KT)+3 : 63;                                        \
    gload16(kbase + (size_t)(k3*64+sr)*64 + ssc*8, &Ks[KST][tid*8]); }         \
  { int v2 = (KT)+2 < 64 ? (KT)+2 : 63;                                        \
    gload16(vbase + (size_t)sr*4096 + v2*64 + ssc*8, &Vs[VST][tid*8]); }       \
  if ((KT)+1 < 64){                                                            \
    __builtin_amdgcn_s_setprio(1);                                             \
    _Pragma("unroll")                                                          \
    for (int n=0;n<4;n++){                                                     \
      int R = n*16 + l15;                                                      \
      f32x4 a_ = {};                                                           \
      _Pragma("unroll")                                                        \
      for (int kk=0;kk<2;kk++){                                                \
        short8 ka = *(const short8*)&Ks[KQK][R*64 + (((kk<<2)+lg) ^ (R&7))*8]; \
        a_ = mfma16(ka, bq[kk], a_);                                           \
      }                                                                        \
      STN[n] = a_;                                                             \
    }                                                                          \
    __builtin_amdgcn_s_setprio(0);                                             \
  }                                                                            \
  /* compiler inserts vmcnt(2) here for kb_ use: retires prev body's K/V */    \
  float p_[4][4]; float ts_ = 0.f;                                             \
  _Pragma("unroll")                                                            \
  for (int n=0;n<4;n++)                                                        \
    _Pragma("unroll")                                                          \
    for (int r=0;r<4;r++){                                                     \
      float e_ = __builtin_amdgcn_exp2f(STC[n][r] + kb_[n][r]);                \
      p_[n][r] = e_; ts_ += e_;                                                \
    }                                                                          \
  ts_ += __shfl_xor(ts_, 16);                                                  \
  ts_ += __shfl_xor(ts_, 32);                                                  \
  l_run += ts_;                                                                \
  _Pragma("unroll")                                                            \
  for (int n=0;n<4;n++){                                                       \
    unsigned p01_, p23_;                                                       \
    asm("v_cvt_pk_bf16_f32 %0, %1, %2" : "=v"(p01_) : "v"(p_[n][0]), "v"(p_[n][1])); \
    asm("v_cvt_pk_bf16_f32 %0, %1, %2" : "=v"(p23_) : "v"(p_[n][2]), "v"(p_[n][3])); \
    int s0_ = n*16 + lg*4;                                                     \
    int off_ = (((s0_>>3) ^ (l15&7))<<3) + (s0_&7);                            \
    *(unsigned*)&Ps[w][l15*64 + off_]     = p01_;                              \
    *(unsigned*)&Ps[w][l15*64 + off_ + 2] = p23_;                              \
  }                                                                            \
  __builtin_amdgcn_s_setprio(1);                                               \
  _Pragma("unroll")                                                            \
  for (int kk=0;kk<2;kk++){                                                    \
    int ch_ = (kk<<2) + lg;                                                    \
    short8 bp_ = *(const short8*)&Ps[w][l15*64 + ((ch_ ^ (l15&7))<<3)];        \
    _Pragma("unroll")                                                          \
    for (int n=0;n<4;n++){                                                     \
      int R = n*16 + l15;                                                      \
      short8 va_ = *(const short8*)&Vs[VPV][R*64 + ((ch_ ^ (R&7))<<3)];        \
      oacc[n] = mfma16(va_, bp_, oacc[n]);                                     \
    }                                                                          \
  }                                                                            \
  __builtin_amdgcn_s_setprio(0);                                               \
  __builtin_amdgcn_s_barrier();                                                \
}

__global__ __launch_bounds__(512) void attn_k(
    const u16* __restrict__ qT, const u16* __restrict__ kT, const u16* __restrict__ vT,
    const int* __restrict__ mask, const float* __restrict__ kbias,
    const float* __restrict__ vmean, u16* __restrict__ o)
{
  __shared__ __align__(16) u16 Ks[4][64*64];
  __shared__ __align__(16) u16 Vs[4][64*64];
  __shared__ __align__(16) u16 Ps[8][16*64];
  const int qt = blockIdx.x, bh = blockIdx.y;
  const int b = bh / 12, h = bh - b*12;
  const int tid = threadIdx.x, w = tid >> 6, l = tid & 63;
  const int l15 = l & 15, lg = l >> 4;

  short8 bq[2];
  {
    const u16* qp = qT + ((size_t)bh*4096 + qt*128 + w*16 + l15)*64 + lg*8;
    bq[0] = *(const short8*)qp;
    bq[1] = *(const short8*)(qp + 32);
  }
  const bool fq = mask[b*4096 + qt*128 + w*16 + l15] != 0;
  const float* kbrow = kbias + b*4096;
  const u16* kbase = kT + (size_t)bh*4096*64;
  const u16* vbase = vT + (size_t)bh*64*4096;

  float l_run = 0.f;
  f32x4 oacc[4] = {};   // O^T[d = n*16+lg*4+r][q = l15]

  const int sr = tid >> 3, ssc = (tid & 7) ^ (sr & 7);

  // prologue: stage K0,K1,K2,V0,V1; drain; QK^T(0)
  gload16(kbase + (size_t)sr*64 + ssc*8,            &Ks[0][tid*8]);
  gload16(kbase + (size_t)(64+sr)*64 + ssc*8,       &Ks[1][tid*8]);
  gload16(kbase + (size_t)(128+sr)*64 + ssc*8,      &Ks[2][tid*8]);
  gload16(vbase + (size_t)sr*4096 + ssc*8,          &Vs[0][tid*8]);
  gload16(vbase + (size_t)sr*4096 + 64 + ssc*8,     &Vs[1][tid*8]);
  asm volatile("s_waitcnt vmcnt(0)" ::: "memory");
  __builtin_amdgcn_s_barrier();

  f32x4 stA[4], stB[4];
  #pragma unroll
  for (int n=0;n<4;n++){
    int R = n*16 + l15;
    f32x4 a_ = {};
    #pragma unroll
    for (int kk=0;kk<2;kk++){
      short8 ka = *(const short8*)&Ks[0][R*64 + (((kk<<2)+lg) ^ (R&7))*8];
      a_ = mfma16(ka, bq[kk], a_);
    }
    stA[n] = a_;
  }
  // no second barrier needed: nothing overwrites Ks[0] until body(1),
  // which is after body(0)'s end barrier.

  for (int kt = 0; kt < 64; kt += 4){
    AT_BODY(kt+0, 1, 3, 0, 2, stA, stB)
    AT_BODY(kt+1, 2, 0, 1, 3, stB, stA)
    AT_BODY(kt+2, 3, 1, 2, 0, stA, stB)
    AT_BODY(kt+3, 0, 2, 3, 1, stB, stA)
  }

  float inv = 1.f / l_run;
  size_t base = ((size_t)b*4096 + qt*128 + w*16 + l15)*768 + h*64 + lg*4;
  #pragma unroll
  for (int n=0;n<4;n++){
    f32x4 vm = *(const f32x4*)(vmean + bh*64 + n*16 + lg*4);
    float v0 = fq ? oacc[n][0]*inv : vm[0]*(1.f/4096.f);
    float v1 = fq ? oacc[n][1]*inv : vm[1]*(1.f/4096.f);
    float v2 = fq ? oacc[n][2]*inv : vm[2]*(1.f/4096.f);
    float v3 = fq ? oacc[n][3]*inv : vm[3]*(1.f/4096.f);
    unsigned q01 = (unsigned)f2b(v0) | ((unsigned)f2b(v1) << 16);
    unsigned q23 = (unsigned)f2b(v2) | ((unsigned)f2b(v3) << 16);
    *(unsigned*)&o[base + n*16]     = q01;
    *(unsigned*)&o[base + n*16 + 2] = q23;
  }
}

// ---------------------------------------------------------------------------
extern "C" void kernel_launch(void* const* d_in, const int* in_sizes, int n_in,
                              void* d_out, int out_size, void* d_ws, size_t ws_size,
                              hipStream_t stream)
{
  const float* x    = (const float*)d_in[0];
  const float* cosb = (const float*)d_in[1];
  const float* sinb = (const float*)d_in[2];
  const float* c    = (const float*)d_in[3];
  const int* amask  = (const int*)d_in[4];
  const float* ln1w = (const float*)d_in[5];
  const float* Wqkv = (const float*)d_in[6];
  const float* Wout = (const float*)d_in[7];
  const float* ln2w = (const float*)d_in[8];
  const float* W1   = (const float*)d_in[9];
  const float* b1   = (const float*)d_in[10];
  const float* W2   = (const float*)d_in[11];
  const float* b2   = (const float*)d_in[12];
  const float* Wada = (const float*)d_in[13];
  const float* bada = (const float*)d_in[14];

  char* ws = (char*)d_ws;
  size_t off = 0;
  auto take = [&](size_t bytes)->char*{
    char* p = ws + off; off = (off + bytes + 255) & ~(size_t)255; return p;
  };
  float* modb = (float*)take(9216*sizeof(float));
  float* kbias= (float*)take(8192*sizeof(float));
  float* vmean= (float*)take(24*64*sizeof(float));
  u16* hdn  = (u16*)take((size_t)8192*768*2);    // hdn, then h2 (bf16)
  u16* bufA = (u16*)take((size_t)8192*3072*2);   // qkv raw, then MLP mid (bf16)
  u16* vS   = (u16*)take((size_t)8192*768*2);    // v (s-major)
  u16* qTb  = (u16*)take((size_t)8192*768*2);
  u16* kTb  = (u16*)take((size_t)8192*768*2);
  u16* vTb  = (u16*)take((size_t)8192*768*2);    // v (d-major)
  u16* ob   = (u16*)take((size_t)8192*768*2);    // attention output (bf16)
  u16* WqkvB= (u16*)take((size_t)2304*768*2);
  u16* WoutB= (u16*)take((size_t)768*768*2);
  u16* W1B  = (u16*)take((size_t)3072*768*2);
  u16* W2B  = (u16*)take((size_t)768*3072*2);
  float* out = (float*)d_out;
  float* x1 = out;                               // reuse d_out for x1 (f32)

  cvt_k<<<(2304*768/4+255)/256, 256, 0, stream>>>(Wqkv, WqkvB, 2304*768/4);
  cvt_k<<<(768*768/4+255)/256, 256, 0, stream>>>(Wout, WoutB, 768*768/4);
  cvt_k<<<(3072*768/4+255)/256, 256, 0, stream>>>(W1, W1B, 3072*768/4);
  cvt_k<<<(768*3072/4+255)/256, 256, 0, stream>>>(W2, W2B, 768*3072/4);
  kbias_k<<<32, 256, 0, stream>>>(amask, kbias, vmean, 8192);

  mod_k  <<<2304, 256, 0, stream>>>(c, Wada, bada, modb);
  ln_mod_k<<<8192, 256, 0, stream>>>(x, hdn, ln1w, modb, 0, 1);
  gemm_k<0><<<dim3(64,18), 256, 0, stream>>>(hdn, WqkvB, bufA, 8192, 2304, 768,
                                             nullptr, nullptr, nullptr);
  rope_k <<<8192, 256, 0, stream>>>(bufA, cosb, sinb, qTb, kTb, vS);
  vtr_k  <<<dim3(64,24), 256, 0, stream>>>(vS, vTb, vmean);
  attn_k <<<dim3(32,24), 512, 0, stream>>>(qTb, kTb, vTb, amask, kbias, vmean, ob);
  gemm_k<1><<<dim3(64,6), 256, 0, stream>>>(ob, WoutB, x1, 8192, 768, 768,
                                            x, modb, nullptr);
  ln_mod_k<<<8192, 256, 0, stream>>>(x1, hdn, ln2w, modb, 3, 4);
  gemm_k<2><<<dim3(64,24), 256, 0, stream>>>(hdn, W1B, bufA, 8192, 3072, 768,
                                             nullptr, nullptr, b1);
  gemm_k<3><<<dim3(64,6), 256, 0, stream>>>(bufA, W2B, out, 8192, 768, 3072,
                                            x1, modb, b2);
}

// Round 13
// 402.824 us; speedup vs baseline: 1.1805x; 1.0004x over previous
//
#include <hip/hip_runtime.h>
#include <stdint.h>

// f32 I/O, bf16 MFMA internals. Attention = exact r11 version (known good):
// swapped QK^T, fixed-shift log2 softmax, QBLK=128, 4-deep K/V rings.
// NEW: RoPE fused into the QKV GEMM epilogue (EPI 4) -> rope_k deleted.
// Masked-q rows = mean(V) (reference's -1e9 bias absorbs scores in f32).

typedef unsigned short u16;
typedef __attribute__((ext_vector_type(4))) float f32x4;
typedef __attribute__((ext_vector_type(8))) short short8;
typedef __attribute__((ext_vector_type(4))) short s16x4;
typedef __attribute__((ext_vector_type(8))) __bf16 bf16x8;

__device__ __forceinline__ float b2f(u16 u){
  union { unsigned int i; float f; } v; v.i = ((unsigned int)u) << 16; return v.f;
}
__device__ __forceinline__ u16 f2b(float f){
  union { float f; unsigned int i; } v; v.f = f;
  unsigned int u = v.i;
  u = u + 0x7FFFu + ((u >> 16) & 1u);   // RNE
  return (u16)(u >> 16);
}
__device__ __forceinline__ f32x4 mfma16(short8 a, short8 b, f32x4 c){
  return __builtin_amdgcn_mfma_f32_16x16x32_bf16(
      __builtin_bit_cast(bf16x8, a), __builtin_bit_cast(bf16x8, b), c, 0, 0, 0);
}
__device__ __forceinline__ void gload16(const void* g, void* l){
  void* gnc = const_cast<void*>(g);
  __builtin_amdgcn_global_load_lds((__attribute__((address_space(1))) void*)gnc,
                                   (__attribute__((address_space(3))) void*)l, 16, 0, 0);
}

// ---------------- f32 -> bf16 weight conversion -----------------------------
__global__ __launch_bounds__(256) void cvt_k(const float* __restrict__ in,
                                             u16* __restrict__ out, int n4)
{
  int i = blockIdx.x*256 + threadIdx.x;
  if (i < n4){
    float4 v = *(const float4*)(in + (size_t)i*4);
    s16x4 o; o[0]=(short)f2b(v.x); o[1]=(short)f2b(v.y);
    o[2]=(short)f2b(v.z); o[3]=(short)f2b(v.w);
    *(s16x4*)(out + (size_t)i*4) = o;
  }
}

// ------- key-bias precompute (fixed shift baked in) + vmean zero ------------
__global__ __launch_bounds__(256) void kbias_k(const int* __restrict__ mask,
                                               float* __restrict__ kb,
                                               float* __restrict__ vm, int n)
{
  int i = blockIdx.x*256 + threadIdx.x;
  if (i < n) kb[i] = mask[i] ? -32.f : -1e30f;
  if (i < 24*64) vm[i] = 0.f;
}

// ---------------- adaLN modulation: mod[b][6*768] = c @ Wada^T + bada --------
__global__ __launch_bounds__(256) void mod_k(const float* __restrict__ c,
    const float* __restrict__ Wada, const float* __restrict__ bada, float* __restrict__ modb)
{
  int o = blockIdx.x*4 + (threadIdx.x >> 6);   // 0..9215
  int l = threadIdx.x & 63;
  int b = o / 4608, j = o - b*4608;
  const float* cp = c + b*768;
  const float* wp = Wada + (size_t)j*768;
  float s = 0.f;
  for (int k = l; k < 768; k += 64) s += cp[k] * wp[k];
  #pragma unroll
  for (int d=1; d<64; d<<=1) s += __shfl_xor(s, d);
  if (l == 0) modb[o] = s + bada[j];
}

// ---------------- LayerNorm (no affine) * w * (1+scale) + shift -> bf16 -----
__global__ __launch_bounds__(256) void ln_mod_k(const float* __restrict__ xin,
    u16* __restrict__ out, const float* __restrict__ lnw, const float* __restrict__ modb,
    int shift_c, int scale_c)
{
  int row = blockIdx.x;             // 0..8191 (b*4096+s)
  int b = row >> 12;
  const float* xp = xin + (size_t)row*768;
  int t = threadIdx.x;
  float v[3]; float s = 0.f, s2 = 0.f;
  #pragma unroll
  for (int i=0;i<3;i++){ float f = xp[t + i*256]; v[i] = f; s += f; s2 += f*f; }
  #pragma unroll
  for (int d=1; d<64; d<<=1){ s += __shfl_xor(s, d); s2 += __shfl_xor(s2, d); }
  __shared__ float rs_[4], rs2_[4];
  int w = t >> 6;
  if ((t & 63) == 0){ rs_[w] = s; rs2_[w] = s2; }
  __syncthreads();
  s  = rs_[0]+rs_[1]+rs_[2]+rs_[3];
  s2 = rs2_[0]+rs2_[1]+rs2_[2]+rs2_[3];
  float mu  = s * (1.f/768.f);
  float var = fmaxf(s2 * (1.f/768.f) - mu*mu, 0.f);
  float rstd = rsqrtf(var + 1e-5f);
  const float* scp = modb + b*4608 + scale_c*768;
  const float* shp = modb + b*4608 + shift_c*768;
  #pragma unroll
  for (int i=0;i<3;i++){
    int d = t + i*256;
    float f = (v[i]-mu)*rstd*lnw[d];
    f = f*(1.f + scp[d]) + shp[d];
    out[(size_t)row*768 + d] = f2b(f);
  }
}

// ---------------- 128x128 BK=64 GEMM, C = A[M,K] @ Bt[N,K]^T, fused epilogues
// EPI 0: C(bf16)=acc.           1: C(f32) = x + gate_msa*acc (x1).
// EPI 2: C(bf16)=gelu(acc+b1).  3: C(f32) = x1 + gate_mlp*(acc+b2).
// EPI 4: fused RoPE + qkv relayout (writes qO/kO/vO, Cv unused).
template<int EPI>
__global__ __launch_bounds__(256) void gemm_k(
    const u16* __restrict__ A, const u16* __restrict__ Bt, void* __restrict__ Cv,
    int M, int N, int K,
    const float* __restrict__ addend, const float* __restrict__ modb,
    const float* __restrict__ bias,
    const float* __restrict__ cosb, const float* __restrict__ sinb,
    u16* __restrict__ qO, u16* __restrict__ kO, u16* __restrict__ vO)
{
  __shared__ __align__(16) u16 As[128*64];
  __shared__ __align__(16) u16 Bs[128*64];
  const int bm = blockIdx.x, bn = blockIdx.y;
  const int tid = threadIdx.x;
  const int w = tid >> 6, l = tid & 63;
  const int wr = w >> 1, wc = w & 1;
  const int l15 = l & 15, lg = l >> 4;
  f32x4 acc[4][4] = {};

  for (int k0 = 0; k0 < K; k0 += 64){
    #pragma unroll
    for (int i=0;i<4;i++){
      int e = i*256 + tid;
      int r = e >> 3, ch = e & 7;
      int sc = ch ^ (r & 7);
      gload16(A  + (size_t)(bm*128 + r)*K + k0 + sc*8, &As[e*8]);
      gload16(Bt + (size_t)(bn*128 + r)*K + k0 + sc*8, &Bs[e*8]);
    }
    __syncthreads();
    #pragma unroll
    for (int kk=0;kk<2;kk++){
      short8 af[4], bfv[4];
      #pragma unroll
      for (int i=0;i<4;i++){
        int ra = wr*64 + i*16 + l15;
        af[i]  = *(const short8*)&As[ra*64 + (((kk*4)+lg) ^ (ra&7))*8];
        int rb = wc*64 + i*16 + l15;
        bfv[i] = *(const short8*)&Bs[rb*64 + (((kk*4)+lg) ^ (rb&7))*8];
      }
      #pragma unroll
      for (int m=0;m<4;m++)
        #pragma unroll
        for (int n=0;n<4;n++)
          acc[m][n] = mfma16(af[m], bfv[n], acc[m][n]);
    }
    __syncthreads();
  }

  if constexpr (EPI == 4){
    // col = bn*128 + wc*64 + n*16 + l15; qi segment and head are block-uniform
    // (768 % 128 == 0). Within-head d = n*16 + l15; rotate-half pair (d,d+32)
    // sits at accumulator n and n+2 of the SAME lane.
    const int colseg = bn*128 + wc*64;
    const int qi = colseg / 768;            // 0=q 1=k 2=v
    const int h  = (colseg - qi*768) >> 6;  // 0..11
    const float qs = (qi == 0) ? 0.1803368801111601f : 1.f;  // 0.125*log2(e)
    u16* dst = (qi == 0) ? qO : (qi == 1) ? kO : vO;
    #pragma unroll
    for (int m=0;m<4;m++){
      #pragma unroll
      for (int r=0;r<4;r++){
        int row = bm*128 + wr*64 + m*16 + lg*4 + r;
        int s = row & 4095, bb = row >> 12;
        size_t obase = ((size_t)(bb*12 + h)*4096 + s)*64;
        #pragma unroll
        for (int n2=0;n2<2;n2++){
          int d1 = n2*16 + l15;            // < 32
          int d2 = d1 + 32;
          float c1 = cosb[s*64 + d1], s1 = sinb[s*64 + d1];
          float c2 = cosb[s*64 + d2], s2 = sinb[s*64 + d2];
          float x1 = acc[m][n2][r], x2 = acc[m][n2+2][r];
          dst[obase + d1] = f2b((x1*c1 - x2*s1)*qs);
          dst[obase + d2] = f2b((x2*c2 + x1*s2)*qs);
        }
      }
    }
    return;
  }

  #pragma unroll
  for (int m=0;m<4;m++){
    int row0 = bm*128 + wr*64 + m*16 + lg*4;
    #pragma unroll
    for (int n=0;n<4;n++){
      int col = bn*128 + wc*64 + n*16 + l15;
      #pragma unroll
      for (int r=0;r<4;r++){
        int row = row0 + r;
        size_t idx = (size_t)row*N + col;
        float v = acc[m][n][r];
        if constexpr (EPI == 0){
          ((u16*)Cv)[idx] = f2b(v);
        } else if constexpr (EPI == 1){
          float g = modb[(row>>12)*4608 + 2*768 + col];   // gate_msa
          ((float*)Cv)[idx] = addend[idx] + g*v;
        } else if constexpr (EPI == 2){
          float u = v + bias[col];
          float t0 = 0.7978845608028654f*(u + 0.044715f*u*u*u);
          ((u16*)Cv)[idx] = f2b(0.5f*u*(1.0f + tanhf(t0)));
        } else if constexpr (EPI == 3){
          float g = modb[(row>>12)*4608 + 5*768 + col];   // gate_mlp
          float u = v + bias[col];
          ((float*)Cv)[idx] = addend[idx] + g*u;
        }
      }
    }
  }
}

// ---------------- V transpose + column-sum atomics --------------------------
__global__ __launch_bounds__(256) void vtr_k(const u16* __restrict__ vS,
                                             u16* __restrict__ vT,
                                             float* __restrict__ vm)
{
  __shared__ __align__(16) u16 tile[64][72];
  __shared__ float cs[4][64];
  int st = blockIdx.x, bh = blockIdx.y;
  int t = threadIdx.x;
  #pragma unroll
  for (int i=0;i<2;i++){
    int e = i*256 + t;
    int r = e >> 3, d0 = (e & 7)*8;
    short8 vv = *(const short8*)(vS + ((size_t)bh*4096 + st*64 + r)*64 + d0);
    *(short8*)&tile[r][d0] = vv;
  }
  __syncthreads();
  #pragma unroll
  for (int i=0;i<2;i++){
    int e = i*256 + t;
    int d = e >> 3, s0 = (e & 7)*8;
    short8 ov;
    #pragma unroll
    for (int k2=0;k2<8;k2++) ov[k2] = (short)tile[s0+k2][d];
    *(short8*)(vT + ((size_t)bh*64 + d)*4096 + st*64 + s0) = ov;
  }
  // column sums of this 64x64 tile -> atomic accumulate
  int d = t & 63, qq = t >> 6;
  float s = 0.f;
  #pragma unroll
  for (int i=0;i<16;i++) s += b2f(tile[qq*16 + i][d]);
  cs[qq][d] = s;
  __syncthreads();
  if (qq == 0) atomicAdd(&vm[bh*64 + d], cs[0][d]+cs[1][d]+cs[2][d]+cs[3][d]);
}

// ---------------- flash attention (exact r11): 4-deep K/V rings -------------
// KQK = (KT+1)%4 (QK read), KST = (KT+3)%4 (K stage),
// VPV = KT%4 (PV read),     VST = (KT+2)%4 (V stage).
#define AT_BODY(KT, KQK, KST, VPV, VST, STC, STN)                              \
{                                                                              \
  f32x4 kb_[4];                                                                \
  _Pragma("unroll")                                                            \
  for (int n=0;n<4;n++)                                                        \
    kb_[n] = *(const f32x4*)(kbrow + (KT)*64 + n*16 + lg*4);                   \
  __builtin_amdgcn_sched_barrier(0);  /* pin kb issue before K/V gloads */     \
  { int k3 = (KT)+3 < 64 ? (KT)+3 : 63;                                        \
    gload16(kbase + (size_t)(k3*64+sr)*64 + ssc*8, &Ks[KST][tid*8]); }         \
  { int v2 = (KT)+2 < 64 ? (KT)+2 : 63;                                        \
    gload16(vbase + (size_t)sr*4096 + v2*64 + ssc*8, &Vs[VST][tid*8]); }       \
  if ((KT)+1 < 64){                                                            \
    __builtin_amdgcn_s_setprio(1);                                             \
    _Pragma("unroll")                                                          \
    for (int n=0;n<4;n++){                                                     \
      int R = n*16 + l15;                                                      \
      f32x4 a_ = {};                                                           \
      _Pragma("unroll")                                                        \
      for (int kk=0;kk<2;kk++){                                                \
        short8 ka = *(const short8*)&Ks[KQK][R*64 + (((kk<<2)+lg) ^ (R&7))*8]; \
        a_ = mfma16(ka, bq[kk], a_);                                           \
      }                                                                        \
      STN[n] = a_;                                                             \
    }                                                                          \
    __builtin_amdgcn_s_setprio(0);                                             \
  }                                                                            \
  /* compiler inserts vmcnt for kb_ use: retires prev body's K/V */            \
  float p_[4][4]; float ts_ = 0.f;                                             \
  _Pragma("unroll")                                                            \
  for (int n=0;n<4;n++)                                                        \
    _Pragma("unroll")                                                          \
    for (int r=0;r<4;r++){                                                     \
      float e_ = __builtin_amdgcn_exp2f(STC[n][r] + kb_[n][r]);                \
      p_[n][r] = e_; ts_ += e_;                                                \
    }                                                                          \
  ts_ += __shfl_xor(ts_, 16);                                                  \
  ts_ += __shfl_xor(ts_, 32);                                                  \
  l_run += ts_;                                                                \
  _Pragma("unroll")                                                            \
  for (int n=0;n<4;n++){                                                       \
    unsigned p01_, p23_;                                                       \
    asm("v_cvt_pk_bf16_f32 %0, %1, %2" : "=v"(p01_) : "v"(p_[n][0]), "v"(p_[n][1])); \
    asm("v_cvt_pk_bf16_f32 %0, %1, %2" : "=v"(p23_) : "v"(p_[n][2]), "v"(p_[n][3])); \
    int s0_ = n*16 + lg*4;                                                     \
    int off_ = (((s0_>>3) ^ (l15&7))<<3) + (s0_&7);                            \
    *(unsigned*)&Ps[w][l15*64 + off_]     = p01_;                              \
    *(unsigned*)&Ps[w][l15*64 + off_ + 2] = p23_;                              \
  }                                                                            \
  __builtin_amdgcn_s_setprio(1);                                               \
  _Pragma("unroll")                                                            \
  for (int kk=0;kk<2;kk++){                                                    \
    int ch_ = (kk<<2) + lg;                                                    \
    short8 bp_ = *(const short8*)&Ps[w][l15*64 + ((ch_ ^ (l15&7))<<3)];        \
    _Pragma("unroll")                                                          \
    for (int n=0;n<4;n++){                                                     \
      int R = n*16 + l15;                                                      \
      short8 va_ = *(const short8*)&Vs[VPV][R*64 + ((ch_ ^ (R&7))<<3)];        \
      oacc[n] = mfma16(va_, bp_, oacc[n]);                                     \
    }                                                                          \
  }                                                                            \
  __builtin_amdgcn_s_setprio(0);                                               \
  __builtin_amdgcn_s_barrier();                                                \
}

__global__ __launch_bounds__(512) void attn_k(
    const u16* __restrict__ qT, const u16* __restrict__ kT, const u16* __restrict__ vT,
    const int* __restrict__ mask, const float* __restrict__ kbias,
    const float* __restrict__ vmean, u16* __restrict__ o)
{
  __shared__ __align__(16) u16 Ks[4][64*64];
  __shared__ __align__(16) u16 Vs[4][64*64];
  __shared__ __align__(16) u16 Ps[8][16*64];
  const int qt = blockIdx.x, bh = blockIdx.y;
  const int b = bh / 12, h = bh - b*12;
  const int tid = threadIdx.x, w = tid >> 6, l = tid & 63;
  const int l15 = l & 15, lg = l >> 4;

  short8 bq[2];
  {
    const u16* qp = qT + ((size_t)bh*4096 + qt*128 + w*16 + l15)*64 + lg*8;
    bq[0] = *(const short8*)qp;
    bq[1] = *(const short8*)(qp + 32);
  }
  const bool fq = mask[b*4096 + qt*128 + w*16 + l15] != 0;
  const float* kbrow = kbias + b*4096;
  const u16* kbase = kT + (size_t)bh*4096*64;
  const u16* vbase = vT + (size_t)bh*64*4096;

  float l_run = 0.f;
  f32x4 oacc[4] = {};   // O^T[d = n*16+lg*4+r][q = l15]

  const int sr = tid >> 3, ssc = (tid & 7) ^ (sr & 7);

  // prologue: stage K0,K1,K2,V0,V1; drain; QK^T(0)
  gload16(kbase + (size_t)sr*64 + ssc*8,            &Ks[0][tid*8]);
  gload16(kbase + (size_t)(64+sr)*64 + ssc*8,       &Ks[1][tid*8]);
  gload16(kbase + (size_t)(128+sr)*64 + ssc*8,      &Ks[2][tid*8]);
  gload16(vbase + (size_t)sr*4096 + ssc*8,          &Vs[0][tid*8]);
  gload16(vbase + (size_t)sr*4096 + 64 + ssc*8,     &Vs[1][tid*8]);
  asm volatile("s_waitcnt vmcnt(0)" ::: "memory");
  __builtin_amdgcn_s_barrier();

  f32x4 stA[4], stB[4];
  #pragma unroll
  for (int n=0;n<4;n++){
    int R = n*16 + l15;
    f32x4 a_ = {};
    #pragma unroll
    for (int kk=0;kk<2;kk++){
      short8 ka = *(const short8*)&Ks[0][R*64 + (((kk<<2)+lg) ^ (R&7))*8];
      a_ = mfma16(ka, bq[kk], a_);
    }
    stA[n] = a_;
  }
  // no second barrier needed: nothing overwrites Ks[0] until body(1),
  // which is after body(0)'s end barrier.

  for (int kt = 0; kt < 64; kt += 4){
    AT_BODY(kt+0, 1, 3, 0, 2, stA, stB)
    AT_BODY(kt+1, 2, 0, 1, 3, stB, stA)
    AT_BODY(kt+2, 3, 1, 2, 0, stA, stB)
    AT_BODY(kt+3, 0, 2, 3, 1, stB, stA)
  }

  float inv = 1.f / l_run;
  size_t base = ((size_t)b*4096 + qt*128 + w*16 + l15)*768 + h*64 + lg*4;
  #pragma unroll
  for (int n=0;n<4;n++){
    f32x4 vm = *(const f32x4*)(vmean + bh*64 + n*16 + lg*4);
    float v0 = fq ? oacc[n][0]*inv : vm[0]*(1.f/4096.f);
    float v1 = fq ? oacc[n][1]*inv : vm[1]*(1.f/4096.f);
    float v2 = fq ? oacc[n][2]*inv : vm[2]*(1.f/4096.f);
    float v3 = fq ? oacc[n][3]*inv : vm[3]*(1.f/4096.f);
    unsigned q01 = (unsigned)f2b(v0) | ((unsigned)f2b(v1) << 16);
    unsigned q23 = (unsigned)f2b(v2) | ((unsigned)f2b(v3) << 16);
    *(unsigned*)&o[base + n*16]     = q01;
    *(unsigned*)&o[base + n*16 + 2] = q23;
  }
}

// ---------------------------------------------------------------------------
extern "C" void kernel_launch(void* const* d_in, const int* in_sizes, int n_in,
                              void* d_out, int out_size, void* d_ws, size_t ws_size,
                              hipStream_t stream)
{
  const float* x    = (const float*)d_in[0];
  const float* cosb = (const float*)d_in[1];
  const float* sinb = (const float*)d_in[2];
  const float* c    = (const float*)d_in[3];
  const int* amask  = (const int*)d_in[4];
  const float* ln1w = (const float*)d_in[5];
  const float* Wqkv = (const float*)d_in[6];
  const float* Wout = (const float*)d_in[7];
  const float* ln2w = (const float*)d_in[8];
  const float* W1   = (const float*)d_in[9];
  const float* b1   = (const float*)d_in[10];
  const float* W2   = (const float*)d_in[11];
  const float* b2   = (const float*)d_in[12];
  const float* Wada = (const float*)d_in[13];
  const float* bada = (const float*)d_in[14];

  char* ws = (char*)d_ws;
  size_t off = 0;
  auto take = [&](size_t bytes)->char*{
    char* p = ws + off; off = (off + bytes + 255) & ~(size_t)255; return p;
  };
  float* modb = (float*)take(9216*sizeof(float));
  float* kbias= (float*)take(8192*sizeof(float));
  float* vmean= (float*)take(24*64*sizeof(float));
  u16* hdn  = (u16*)take((size_t)8192*768*2);    // hdn, then h2 (bf16)
  u16* bufA = (u16*)take((size_t)8192*3072*2);   // MLP mid (bf16)
  u16* vS   = (u16*)take((size_t)8192*768*2);    // v (s-major)
  u16* qTb  = (u16*)take((size_t)8192*768*2);
  u16* kTb  = (u16*)take((size_t)8192*768*2);
  u16* vTb  = (u16*)take((size_t)8192*768*2);    // v (d-major)
  u16* ob   = (u16*)take((size_t)8192*768*2);    // attention output (bf16)
  u16* WqkvB= (u16*)take((size_t)2304*768*2);
  u16* WoutB= (u16*)take((size_t)768*768*2);
  u16* W1B  = (u16*)take((size_t)3072*768*2);
  u16* W2B  = (u16*)take((size_t)768*3072*2);
  float* out = (float*)d_out;
  float* x1 = out;                               // reuse d_out for x1 (f32)

  cvt_k<<<(2304*768/4+255)/256, 256, 0, stream>>>(Wqkv, WqkvB, 2304*768/4);
  cvt_k<<<(768*768/4+255)/256, 256, 0, stream>>>(Wout, WoutB, 768*768/4);
  cvt_k<<<(3072*768/4+255)/256, 256, 0, stream>>>(W1, W1B, 3072*768/4);
  cvt_k<<<(768*3072/4+255)/256, 256, 0, stream>>>(W2, W2B, 768*3072/4);
  kbias_k<<<32, 256, 0, stream>>>(amask, kbias, vmean, 8192);

  mod_k  <<<2304, 256, 0, stream>>>(c, Wada, bada, modb);
  ln_mod_k<<<8192, 256, 0, stream>>>(x, hdn, ln1w, modb, 0, 1);
  gemm_k<4><<<dim3(64,18), 256, 0, stream>>>(hdn, WqkvB, nullptr, 8192, 2304, 768,
                                             nullptr, nullptr, nullptr,
                                             cosb, sinb, qTb, kTb, vS);
  vtr_k  <<<dim3(64,24), 256, 0, stream>>>(vS, vTb, vmean);
  attn_k <<<dim3(32,24), 512, 0, stream>>>(qTb, kTb, vTb, amask, kbias, vmean, ob);
  gemm_k<1><<<dim3(64,6), 256, 0, stream>>>(ob, WoutB, x1, 8192, 768, 768,
                                            x, modb, nullptr,
                                            nullptr, nullptr, nullptr, nullptr, nullptr);
  ln_mod_k<<<8192, 256, 0, stream>>>(x1, hdn, ln2w, modb, 3, 4);
  gemm_k<2><<<dim3(64,24), 256, 0, stream>>>(hdn, W1B, bufA, 8192, 3072, 768,
                                             nullptr, nullptr, b1,
                                             nullptr, nullptr, nullptr, nullptr, nullptr);
  gemm_k<3><<<dim3(64,6), 256, 0, stream>>>(bufA, W2B, out, 8192, 768, 3072,
                                            x1, modb, b2,
                                            nullptr, nullptr, nullptr, nullptr, nullptr);
}

// Round 14
// 396.036 us; speedup vs baseline: 1.2007x; 1.0171x over previous
//
#include <hip/hip_runtime.h>
#include <stdint.h>

// f32 I/O, bf16 MFMA internals. Attention = r11/r13 structure (known good):
// swapped QK^T, fixed-shift log2 softmax, QBLK=128, 4-deep K/V rings.
// r14: attn __launch_bounds__(512,4) to unlock 128-VGPR address hoisting
// (occupancy is LDS-bound at 2 blocks/CU = 4 waves/SIMD, free up to 128);
// 4 cvt launches merged into one. RoPE fused in QKV GEMM epilogue (EPI 4).
// Masked-q rows = mean(V) (reference's -1e9 bias absorbs scores in f32).

typedef unsigned short u16;
typedef __attribute__((ext_vector_type(4))) float f32x4;
typedef __attribute__((ext_vector_type(8))) short short8;
typedef __attribute__((ext_vector_type(4))) short s16x4;
typedef __attribute__((ext_vector_type(8))) __bf16 bf16x8;

__device__ __forceinline__ float b2f(u16 u){
  union { unsigned int i; float f; } v; v.i = ((unsigned int)u) << 16; return v.f;
}
__device__ __forceinline__ u16 f2b(float f){
  union { float f; unsigned int i; } v; v.f = f;
  unsigned int u = v.i;
  u = u + 0x7FFFu + ((u >> 16) & 1u);   // RNE
  return (u16)(u >> 16);
}
__device__ __forceinline__ f32x4 mfma16(short8 a, short8 b, f32x4 c){
  return __builtin_amdgcn_mfma_f32_16x16x32_bf16(
      __builtin_bit_cast(bf16x8, a), __builtin_bit_cast(bf16x8, b), c, 0, 0, 0);
}
__device__ __forceinline__ void gload16(const void* g, void* l){
  void* gnc = const_cast<void*>(g);
  __builtin_amdgcn_global_load_lds((__attribute__((address_space(1))) void*)gnc,
                                   (__attribute__((address_space(3))) void*)l, 16, 0, 0);
}

// ---------------- merged f32 -> bf16 weight conversion (4 segments) ---------
// Explicit per-segment dst pointers (no ws-layout assumption). Grid covers
// exactly 442368+147456+589824+589824 = 1769472 float4 units = 6912 blocks.
__global__ __launch_bounds__(256) void cvt4_k(
    const float* __restrict__ s0, u16* __restrict__ d0,
    const float* __restrict__ s1, u16* __restrict__ d1,
    const float* __restrict__ s2, u16* __restrict__ d2,
    const float* __restrict__ s3, u16* __restrict__ d3)
{
  int i = blockIdx.x*256 + threadIdx.x;
  const float* src; u16* dst; int j = i;
  if (j < 442368){ src = s0; dst = d0; }
  else if ((j -= 442368) < 147456){ src = s1; dst = d1; }
  else if ((j -= 147456) < 589824){ src = s2; dst = d2; }
  else { j -= 589824; src = s3; dst = d3; }
  float4 v = *(const float4*)(src + (size_t)j*4);
  s16x4 o; o[0]=(short)f2b(v.x); o[1]=(short)f2b(v.y);
  o[2]=(short)f2b(v.z); o[3]=(short)f2b(v.w);
  *(s16x4*)(dst + (size_t)j*4) = o;
}

// ------- key-bias precompute (fixed shift baked in) + vmean zero ------------
__global__ __launch_bounds__(256) void kbias_k(const int* __restrict__ mask,
                                               float* __restrict__ kb,
                                               float* __restrict__ vm, int n)
{
  int i = blockIdx.x*256 + threadIdx.x;
  if (i < n) kb[i] = mask[i] ? -32.f : -1e30f;
  if (i < 24*64) vm[i] = 0.f;
}

// ---------------- adaLN modulation: mod[b][6*768] = c @ Wada^T + bada --------
__global__ __launch_bounds__(256) void mod_k(const float* __restrict__ c,
    const float* __restrict__ Wada, const float* __restrict__ bada, float* __restrict__ modb)
{
  int o = blockIdx.x*4 + (threadIdx.x >> 6);   // 0..9215
  int l = threadIdx.x & 63;
  int b = o / 4608, j = o - b*4608;
  const float* cp = c + b*768;
  const float* wp = Wada + (size_t)j*768;
  float s = 0.f;
  for (int k = l; k < 768; k += 64) s += cp[k] * wp[k];
  #pragma unroll
  for (int d=1; d<64; d<<=1) s += __shfl_xor(s, d);
  if (l == 0) modb[o] = s + bada[j];
}

// ---------------- LayerNorm (no affine) * w * (1+scale) + shift -> bf16 -----
__global__ __launch_bounds__(256) void ln_mod_k(const float* __restrict__ xin,
    u16* __restrict__ out, const float* __restrict__ lnw, const float* __restrict__ modb,
    int shift_c, int scale_c)
{
  int row = blockIdx.x;             // 0..8191 (b*4096+s)
  int b = row >> 12;
  const float* xp = xin + (size_t)row*768;
  int t = threadIdx.x;
  float v[3]; float s = 0.f, s2 = 0.f;
  #pragma unroll
  for (int i=0;i<3;i++){ float f = xp[t + i*256]; v[i] = f; s += f; s2 += f*f; }
  #pragma unroll
  for (int d=1; d<64; d<<=1){ s += __shfl_xor(s, d); s2 += __shfl_xor(s2, d); }
  __shared__ float rs_[4], rs2_[4];
  int w = t >> 6;
  if ((t & 63) == 0){ rs_[w] = s; rs2_[w] = s2; }
  __syncthreads();
  s  = rs_[0]+rs_[1]+rs_[2]+rs_[3];
  s2 = rs2_[0]+rs2_[1]+rs2_[2]+rs2_[3];
  float mu  = s * (1.f/768.f);
  float var = fmaxf(s2 * (1.f/768.f) - mu*mu, 0.f);
  float rstd = rsqrtf(var + 1e-5f);
  const float* scp = modb + b*4608 + scale_c*768;
  const float* shp = modb + b*4608 + shift_c*768;
  #pragma unroll
  for (int i=0;i<3;i++){
    int d = t + i*256;
    float f = (v[i]-mu)*rstd*lnw[d];
    f = f*(1.f + scp[d]) + shp[d];
    out[(size_t)row*768 + d] = f2b(f);
  }
}

// ---------------- 128x128 BK=64 GEMM, C = A[M,K] @ Bt[N,K]^T, fused epilogues
// EPI 0: C(bf16)=acc.           1: C(f32) = x + gate_msa*acc (x1).
// EPI 2: C(bf16)=gelu(acc+b1).  3: C(f32) = x1 + gate_mlp*(acc+b2).
// EPI 4: fused RoPE + qkv relayout (writes qO/kO/vO, Cv unused).
template<int EPI>
__global__ __launch_bounds__(256) void gemm_k(
    const u16* __restrict__ A, const u16* __restrict__ Bt, void* __restrict__ Cv,
    int M, int N, int K,
    const float* __restrict__ addend, const float* __restrict__ modb,
    const float* __restrict__ bias,
    const float* __restrict__ cosb, const float* __restrict__ sinb,
    u16* __restrict__ qO, u16* __restrict__ kO, u16* __restrict__ vO)
{
  __shared__ __align__(16) u16 As[128*64];
  __shared__ __align__(16) u16 Bs[128*64];
  const int bm = blockIdx.x, bn = blockIdx.y;
  const int tid = threadIdx.x;
  const int w = tid >> 6, l = tid & 63;
  const int wr = w >> 1, wc = w & 1;
  const int l15 = l & 15, lg = l >> 4;
  f32x4 acc[4][4] = {};

  for (int k0 = 0; k0 < K; k0 += 64){
    #pragma unroll
    for (int i=0;i<4;i++){
      int e = i*256 + tid;
      int r = e >> 3, ch = e & 7;
      int sc = ch ^ (r & 7);
      gload16(A  + (size_t)(bm*128 + r)*K + k0 + sc*8, &As[e*8]);
      gload16(Bt + (size_t)(bn*128 + r)*K + k0 + sc*8, &Bs[e*8]);
    }
    __syncthreads();
    #pragma unroll
    for (int kk=0;kk<2;kk++){
      short8 af[4], bfv[4];
      #pragma unroll
      for (int i=0;i<4;i++){
        int ra = wr*64 + i*16 + l15;
        af[i]  = *(const short8*)&As[ra*64 + (((kk*4)+lg) ^ (ra&7))*8];
        int rb = wc*64 + i*16 + l15;
        bfv[i] = *(const short8*)&Bs[rb*64 + (((kk*4)+lg) ^ (rb&7))*8];
      }
      #pragma unroll
      for (int m=0;m<4;m++)
        #pragma unroll
        for (int n=0;n<4;n++)
          acc[m][n] = mfma16(af[m], bfv[n], acc[m][n]);
    }
    __syncthreads();
  }

  if constexpr (EPI == 4){
    const int colseg = bn*128 + wc*64;
    const int qi = colseg / 768;            // 0=q 1=k 2=v
    const int h  = (colseg - qi*768) >> 6;  // 0..11
    const float qs = (qi == 0) ? 0.1803368801111601f : 1.f;  // 0.125*log2(e)
    u16* dst = (qi == 0) ? qO : (qi == 1) ? kO : vO;
    #pragma unroll
    for (int m=0;m<4;m++){
      #pragma unroll
      for (int r=0;r<4;r++){
        int row = bm*128 + wr*64 + m*16 + lg*4 + r;
        int s = row & 4095, bb = row >> 12;
        size_t obase = ((size_t)(bb*12 + h)*4096 + s)*64;
        #pragma unroll
        for (int n2=0;n2<2;n2++){
          int d1 = n2*16 + l15;            // < 32
          int d2 = d1 + 32;
          float c1 = cosb[s*64 + d1], s1 = sinb[s*64 + d1];
          float c2 = cosb[s*64 + d2], s2 = sinb[s*64 + d2];
          float x1 = acc[m][n2][r], x2 = acc[m][n2+2][r];
          dst[obase + d1] = f2b((x1*c1 - x2*s1)*qs);
          dst[obase + d2] = f2b((x2*c2 + x1*s2)*qs);
        }
      }
    }
    return;
  }

  #pragma unroll
  for (int m=0;m<4;m++){
    int row0 = bm*128 + wr*64 + m*16 + lg*4;
    #pragma unroll
    for (int n=0;n<4;n++){
      int col = bn*128 + wc*64 + n*16 + l15;
      #pragma unroll
      for (int r=0;r<4;r++){
        int row = row0 + r;
        size_t idx = (size_t)row*N + col;
        float v = acc[m][n][r];
        if constexpr (EPI == 0){
          ((u16*)Cv)[idx] = f2b(v);
        } else if constexpr (EPI == 1){
          float g = modb[(row>>12)*4608 + 2*768 + col];   // gate_msa
          ((float*)Cv)[idx] = addend[idx] + g*v;
        } else if constexpr (EPI == 2){
          float u = v + bias[col];
          float t0 = 0.7978845608028654f*(u + 0.044715f*u*u*u);
          ((u16*)Cv)[idx] = f2b(0.5f*u*(1.0f + tanhf(t0)));
        } else if constexpr (EPI == 3){
          float g = modb[(row>>12)*4608 + 5*768 + col];   // gate_mlp
          float u = v + bias[col];
          ((float*)Cv)[idx] = addend[idx] + g*u;
        }
      }
    }
  }
}

// ---------------- V transpose + column-sum atomics --------------------------
__global__ __launch_bounds__(256) void vtr_k(const u16* __restrict__ vS,
                                             u16* __restrict__ vT,
                                             float* __restrict__ vm)
{
  __shared__ __align__(16) u16 tile[64][72];
  __shared__ float cs[4][64];
  int st = blockIdx.x, bh = blockIdx.y;
  int t = threadIdx.x;
  #pragma unroll
  for (int i=0;i<2;i++){
    int e = i*256 + t;
    int r = e >> 3, d0 = (e & 7)*8;
    short8 vv = *(const short8*)(vS + ((size_t)bh*4096 + st*64 + r)*64 + d0);
    *(short8*)&tile[r][d0] = vv;
  }
  __syncthreads();
  #pragma unroll
  for (int i=0;i<2;i++){
    int e = i*256 + t;
    int d = e >> 3, s0 = (e & 7)*8;
    short8 ov;
    #pragma unroll
    for (int k2=0;k2<8;k2++) ov[k2] = (short)tile[s0+k2][d];
    *(short8*)(vT + ((size_t)bh*64 + d)*4096 + st*64 + s0) = ov;
  }
  int d = t & 63, qq = t >> 6;
  float s = 0.f;
  #pragma unroll
  for (int i=0;i<16;i++) s += b2f(tile[qq*16 + i][d]);
  cs[qq][d] = s;
  __syncthreads();
  if (qq == 0) atomicAdd(&vm[bh*64 + d], cs[0][d]+cs[1][d]+cs[2][d]+cs[3][d]);
}

// ---------------- flash attention: 4-deep K/V rings -------------------------
// KQK = (KT+1)%4 (QK read), KST = (KT+3)%4 (K stage),
// VPV = KT%4 (PV read),     VST = (KT+2)%4 (V stage).
#define AT_BODY(KT, KQK, KST, VPV, VST, STC, STN)                              \
{                                                                              \
  f32x4 kb_[4];                                                                \
  _Pragma("unroll")                                                            \
  for (int n=0;n<4;n++)                                                        \
    kb_[n] = *(const f32x4*)(kbrow + (KT)*64 + n*16 + lg*4);                   \
  __builtin_amdgcn_sched_barrier(0);  /* pin kb issue before K/V gloads */     \
  { int k3 = (KT)+3 < 64 ? (KT)+3 : 63;                                        \
    gload16(kbase + (size_t)(k3*64+sr)*64 + ssc*8, &Ks[KST][tid*8]); }         \
  { int v2 = (KT)+2 < 64 ? (KT)+2 : 63;                                        \
    gload16(vbase + (size_t)sr*4096 + v2*64 + ssc*8, &Vs[VST][tid*8]); }       \
  if ((KT)+1 < 64){                                                            \
    __builtin_amdgcn_s_setprio(1);                                             \
    _Pragma("unroll")                                                          \
    for (int n=0;n<4;n++){                                                     \
      int R = n*16 + l15;                                                      \
      f32x4 a_ = {};                                                           \
      _Pragma("unroll")                                                        \
      for (int kk=0;kk<2;kk++){                                                \
        short8 ka = *(const short8*)&Ks[KQK][R*64 + (((kk<<2)+lg) ^ (R&7))*8]; \
        a_ = mfma16(ka, bq[kk], a_);                                           \
      }                                                                        \
      STN[n] = a_;                                                             \
    }                                                                          \
    __builtin_amdgcn_s_setprio(0);                                             \
  }                                                                            \
  /* compiler inserts vmcnt for kb_ use: retires prev body's K/V */            \
  float p_[4][4]; float ts_ = 0.f;                                             \
  _Pragma("unroll")                                                            \
  for (int n=0;n<4;n++)                                                        \
    _Pragma("unroll")                                                          \
    for (int r=0;r<4;r++){                                                     \
      float e_ = __builtin_amdgcn_exp2f(STC[n][r] + kb_[n][r]);                \
      p_[n][r] = e_; ts_ += e_;                                                \
    }                                                                          \
  ts_ += __shfl_xor(ts_, 16);                                                  \
  ts_ += __shfl_xor(ts_, 32);                                                  \
  l_run += ts_;                                                                \
  _Pragma("unroll")                                                            \
  for (int n=0;n<4;n++){                                                       \
    unsigned p01_, p23_;                                                       \
    asm("v_cvt_pk_bf16_f32 %0, %1, %2" : "=v"(p01_) : "v"(p_[n][0]), "v"(p_[n][1])); \
    asm("v_cvt_pk_bf16_f32 %0, %1, %2" : "=v"(p23_) : "v"(p_[n][2]), "v"(p_[n][3])); \
    int s0_ = n*16 + lg*4;                                                     \
    int off_ = (((s0_>>3) ^ (l15&7))<<3) + (s0_&7);                            \
    *(unsigned*)&Ps[w][l15*64 + off_]     = p01_;                              \
    *(unsigned*)&Ps[w][l15*64 + off_ + 2] = p23_;                              \
  }                                                                            \
  __builtin_amdgcn_s_setprio(1);                                               \
  _Pragma("unroll")                                                            \
  for (int kk=0;kk<2;kk++){                                                    \
    int ch_ = (kk<<2) + lg;                                                    \
    short8 bp_ = *(const short8*)&Ps[w][l15*64 + ((ch_ ^ (l15&7))<<3)];        \
    _Pragma("unroll")                                                          \
    for (int n=0;n<4;n++){                                                     \
      int R = n*16 + l15;                                                      \
      short8 va_ = *(const short8*)&Vs[VPV][R*64 + ((ch_ ^ (R&7))<<3)];        \
      oacc[n] = mfma16(va_, bp_, oacc[n]);                                     \
    }                                                                          \
  }                                                                            \
  __builtin_amdgcn_s_setprio(0);                                               \
  __builtin_amdgcn_s_barrier();                                                \
}

__global__ __launch_bounds__(512, 4) void attn_k(
    const u16* __restrict__ qT, const u16* __restrict__ kT, const u16* __restrict__ vT,
    const int* __restrict__ mask, const float* __restrict__ kbias,
    const float* __restrict__ vmean, u16* __restrict__ o)
{
  __shared__ __align__(16) u16 Ks[4][64*64];
  __shared__ __align__(16) u16 Vs[4][64*64];
  __shared__ __align__(16) u16 Ps[8][16*64];
  const int qt = blockIdx.x, bh = blockIdx.y;
  const int b = bh / 12, h = bh - b*12;
  const int tid = threadIdx.x, w = tid >> 6, l = tid & 63;
  const int l15 = l & 15, lg = l >> 4;

  short8 bq[2];
  {
    const u16* qp = qT + ((size_t)bh*4096 + qt*128 + w*16 + l15)*64 + lg*8;
    bq[0] = *(const short8*)qp;
    bq[1] = *(const short8*)(qp + 32);
  }
  const bool fq = mask[b*4096 + qt*128 + w*16 + l15] != 0;
  const float* kbrow = kbias + b*4096;
  const u16* kbase = kT + (size_t)bh*4096*64;
  const u16* vbase = vT + (size_t)bh*64*4096;

  float l_run = 0.f;
  f32x4 oacc[4] = {};   // O^T[d = n*16+lg*4+r][q = l15]

  const int sr = tid >> 3, ssc = (tid & 7) ^ (sr & 7);

  // prologue: stage K0,K1,K2,V0,V1; drain; QK^T(0)
  gload16(kbase + (size_t)sr*64 + ssc*8,            &Ks[0][tid*8]);
  gload16(kbase + (size_t)(64+sr)*64 + ssc*8,       &Ks[1][tid*8]);
  gload16(kbase + (size_t)(128+sr)*64 + ssc*8,      &Ks[2][tid*8]);
  gload16(vbase + (size_t)sr*4096 + ssc*8,          &Vs[0][tid*8]);
  gload16(vbase + (size_t)sr*4096 + 64 + ssc*8,     &Vs[1][tid*8]);
  asm volatile("s_waitcnt vmcnt(0)" ::: "memory");
  __builtin_amdgcn_s_barrier();

  f32x4 stA[4], stB[4];
  #pragma unroll
  for (int n=0;n<4;n++){
    int R = n*16 + l15;
    f32x4 a_ = {};
    #pragma unroll
    for (int kk=0;kk<2;kk++){
      short8 ka = *(const short8*)&Ks[0][R*64 + (((kk<<2)+lg) ^ (R&7))*8];
      a_ = mfma16(ka, bq[kk], a_);
    }
    stA[n] = a_;
  }
  // no second barrier needed: nothing overwrites Ks[0] until body(1),
  // which is after body(0)'s end barrier.

  for (int kt = 0; kt < 64; kt += 4){
    AT_BODY(kt+0, 1, 3, 0, 2, stA, stB)
    AT_BODY(kt+1, 2, 0, 1, 3, stB, stA)
    AT_BODY(kt+2, 3, 1, 2, 0, stA, stB)
    AT_BODY(kt+3, 0, 2, 3, 1, stB, stA)
  }

  float inv = 1.f / l_run;
  size_t base = ((size_t)b*4096 + qt*128 + w*16 + l15)*768 + h*64 + lg*4;
  #pragma unroll
  for (int n=0;n<4;n++){
    f32x4 vm = *(const f32x4*)(vmean + bh*64 + n*16 + lg*4);
    float v0 = fq ? oacc[n][0]*inv : vm[0]*(1.f/4096.f);
    float v1 = fq ? oacc[n][1]*inv : vm[1]*(1.f/4096.f);
    float v2 = fq ? oacc[n][2]*inv : vm[2]*(1.f/4096.f);
    float v3 = fq ? oacc[n][3]*inv : vm[3]*(1.f/4096.f);
    unsigned q01 = (unsigned)f2b(v0) | ((unsigned)f2b(v1) << 16);
    unsigned q23 = (unsigned)f2b(v2) | ((unsigned)f2b(v3) << 16);
    *(unsigned*)&o[base + n*16]     = q01;
    *(unsigned*)&o[base + n*16 + 2] = q23;
  }
}

// ---------------------------------------------------------------------------
extern "C" void kernel_launch(void* const* d_in, const int* in_sizes, int n_in,
                              void* d_out, int out_size, void* d_ws, size_t ws_size,
                              hipStream_t stream)
{
  const float* x    = (const float*)d_in[0];
  const float* cosb = (const float*)d_in[1];
  const float* sinb = (const float*)d_in[2];
  const float* c    = (const float*)d_in[3];
  const int* amask  = (const int*)d_in[4];
  const float* ln1w = (const float*)d_in[5];
  const float* Wqkv = (const float*)d_in[6];
  const float* Wout = (const float*)d_in[7];
  const float* ln2w = (const float*)d_in[8];
  const float* W1   = (const float*)d_in[9];
  const float* b1   = (const float*)d_in[10];
  const float* W2   = (const float*)d_in[11];
  const float* b2   = (const float*)d_in[12];
  const float* Wada = (const float*)d_in[13];
  const float* bada = (const float*)d_in[14];

  char* ws = (char*)d_ws;
  size_t off = 0;
  auto take = [&](size_t bytes)->char*{
    char* p = ws + off; off = (off + bytes + 255) & ~(size_t)255; return p;
  };
  float* modb = (float*)take(9216*sizeof(float));
  float* kbias= (float*)take(8192*sizeof(float));
  float* vmean= (float*)take(24*64*sizeof(float));
  u16* hdn  = (u16*)take((size_t)8192*768*2);    // hdn, then h2 (bf16)
  u16* bufA = (u16*)take((size_t)8192*3072*2);   // MLP mid (bf16)
  u16* vS   = (u16*)take((size_t)8192*768*2);    // v (s-major)
  u16* qTb  = (u16*)take((size_t)8192*768*2);
  u16* kTb  = (u16*)take((size_t)8192*768*2);
  u16* vTb  = (u16*)take((size_t)8192*768*2);    // v (d-major)
  u16* ob   = (u16*)take((size_t)8192*768*2);    // attention output (bf16)
  u16* WqkvB= (u16*)take((size_t)2304*768*2);
  u16* WoutB= (u16*)take((size_t)768*768*2);
  u16* W1B  = (u16*)take((size_t)3072*768*2);
  u16* W2B  = (u16*)take((size_t)768*3072*2);
  float* out = (float*)d_out;
  float* x1 = out;                               // reuse d_out for x1 (f32)

  cvt4_k<<<6912, 256, 0, stream>>>(Wqkv, WqkvB, Wout, WoutB, W1, W1B, W2, W2B);
  kbias_k<<<32, 256, 0, stream>>>(amask, kbias, vmean, 8192);

  mod_k  <<<2304, 256, 0, stream>>>(c, Wada, bada, modb);
  ln_mod_k<<<8192, 256, 0, stream>>>(x, hdn, ln1w, modb, 0, 1);
  gemm_k<4><<<dim3(64,18), 256, 0, stream>>>(hdn, WqkvB, nullptr, 8192, 2304, 768,
                                             nullptr, nullptr, nullptr,
                                             cosb, sinb, qTb, kTb, vS);
  vtr_k  <<<dim3(64,24), 256, 0, stream>>>(vS, vTb, vmean);
  attn_k <<<dim3(32,24), 512, 0, stream>>>(qTb, kTb, vTb, amask, kbias, vmean, ob);
  gemm_k<1><<<dim3(64,6), 256, 0, stream>>>(ob, WoutB, x1, 8192, 768, 768,
                                            x, modb, nullptr,
                                            nullptr, nullptr, nullptr, nullptr, nullptr);
  ln_mod_k<<<8192, 256, 0, stream>>>(x1, hdn, ln2w, modb, 3, 4);
  gemm_k<2><<<dim3(64,24), 256, 0, stream>>>(hdn, W1B, bufA, 8192, 3072, 768,
                                             nullptr, nullptr, b1,
                                             nullptr, nullptr, nullptr, nullptr, nullptr);
  gemm_k<3><<<dim3(64,6), 256, 0, stream>>>(bufA, W2B, out, 8192, 768, 3072,
                                            x1, modb, b2,
                                            nullptr, nullptr, nullptr, nullptr, nullptr);
}